// Round 1
// baseline (154.995 us; speedup 1.0000x reference)
//
#include <hip/hip_runtime.h>
#include <hip/hip_bf16.h>

#define B_ 4
#define N_ 2048
#define C_ 256
#define H_ 4
#define D_ 64

typedef __attribute__((ext_vector_type(8))) short bf16x8;
typedef __attribute__((ext_vector_type(4))) float f32x4;

#define LOG2E 1.4426950408889634f

// f32 -> bf16 round-to-nearest-even (scalar)
static __device__ inline unsigned short f2bf(float f) {
    unsigned u = __builtin_bit_cast(unsigned, f);
    unsigned r = (u + 0x7fffu + ((u >> 16) & 1u)) >> 16;
    return (unsigned short)r;
}
static __device__ inline float bf2f(unsigned short h) {
    unsigned u = ((unsigned)h) << 16;
    return __builtin_bit_cast(float, u);
}
// packed pair f32 -> bf16x2 (v_cvt_pk_bf16_f32 where available)
static __device__ inline unsigned pack2(float a, float b) {
    __hip_bfloat162 h = __float22bfloat162_rn(make_float2(a, b));
    unsigned u;
    __builtin_memcpy(&u, &h, 4);
    return u;
}
static __device__ inline bf16x8 ld_frag(const unsigned short* p) {
    return __builtin_bit_cast(bf16x8, *(const uint4*)p);
}

// ---------------- cvt prepass: x / qkv_w / proj_w -> bf16 ----------------
__global__ __launch_bounds__(256) void cvt_kernel(
    const float* __restrict__ x, const float* __restrict__ qkv_w,
    const float* __restrict__ proj_w,
    unsigned short* __restrict__ xb, unsigned short* __restrict__ wqb,
    unsigned short* __restrict__ wpb)
{
    const int bid = blockIdx.x, tid = threadIdx.x;
    const float* s; unsigned short* d; int i;
    if (bid < 1024)      { s = x;      d = xb;  i = (bid * 256 + tid) * 8; }
    else if (bid < 1120) { s = qkv_w;  d = wqb; i = ((bid - 1024) * 256 + tid) * 8; }
    else                 { s = proj_w; d = wpb; i = ((bid - 1120) * 256 + tid) * 8; }
    float4 a = *(const float4*)(s + i);
    float4 b = *(const float4*)(s + i + 4);
    uint4 u;
    u.x = pack2(a.x, a.y); u.y = pack2(a.z, a.w);
    u.z = pack2(b.x, b.y); u.w = pack2(b.z, b.w);
    *(uint4*)(d + i) = u;
}

// ---------------- QKV GEMM: bf16, 128x128 tile, 4 waves 2x2, BK=32 ----------
// Q pre-scaled by 0.125*log2e. V written transposed+permuted:
// vt[bh][d][n_perm], perm within 64-block: p = 4*(n&15)+((n>>4)&3).
__global__ __launch_bounds__(256) void qkv_gemm(
    const unsigned short* __restrict__ xb, const unsigned short* __restrict__ wb,
    const float* __restrict__ bias, unsigned short* __restrict__ qb,
    unsigned short* __restrict__ kb, unsigned short* __restrict__ vt)
{
    __shared__ __align__(16) unsigned short As[128 * 40];
    __shared__ __align__(16) unsigned short Bs[128 * 40];
    const int m0 = blockIdx.x * 128, o0 = blockIdx.y * 128;
    const int tid = threadIdx.x;
    const int wave = tid >> 6, lane = tid & 63, quad = lane >> 4, l16 = lane & 15;
    const int wy = wave >> 1, wx = wave & 1;

    f32x4 acc[4][4];
    #pragma unroll
    for (int i = 0; i < 4; ++i)
        #pragma unroll
        for (int j = 0; j < 4; ++j) acc[i][j] = (f32x4){0.f, 0.f, 0.f, 0.f};

    const int srow = tid >> 1, soff = (tid & 1) * 16;   // 128 rows x 32 cols staging

    for (int k0 = 0; k0 < 256; k0 += 32) {
        __syncthreads();
        {
            const unsigned short* sa = &xb[(size_t)(m0 + srow) * 256 + k0 + soff];
            const unsigned short* sb = &wb[(size_t)(o0 + srow) * 256 + k0 + soff];
            *(uint4*)&As[srow * 40 + soff + 0] = *(const uint4*)(sa + 0);
            *(uint4*)&As[srow * 40 + soff + 8] = *(const uint4*)(sa + 8);
            *(uint4*)&Bs[srow * 40 + soff + 0] = *(const uint4*)(sb + 0);
            *(uint4*)&Bs[srow * 40 + soff + 8] = *(const uint4*)(sb + 8);
        }
        __syncthreads();
        bf16x8 a[4], b[4];
        #pragma unroll
        for (int mt = 0; mt < 4; ++mt) a[mt] = ld_frag(&As[(wy * 64 + mt * 16 + l16) * 40 + quad * 8]);
        #pragma unroll
        for (int nt = 0; nt < 4; ++nt) b[nt] = ld_frag(&Bs[(wx * 64 + nt * 16 + l16) * 40 + quad * 8]);
        #pragma unroll
        for (int mt = 0; mt < 4; ++mt)
            #pragma unroll
            for (int nt = 0; nt < 4; ++nt)
                acc[mt][nt] = __builtin_amdgcn_mfma_f32_16x16x32_bf16(a[mt], b[nt], acc[mt][nt], 0, 0, 0);
    }

    const int sec = o0 + wx * 64;            // this wave's 64 output cols
    const int three = sec >> 8;
    const int h = (sec >> 6) & 3;
    const int b = m0 >> 11;
    float bv[4];
    #pragma unroll
    for (int nt = 0; nt < 4; ++nt) bv[nt] = bias[sec + nt * 16 + l16];

    if (three == 2) {
        // V: n = m0 + wy*64 + mt*16 + quad*4 + r; p = 16*quad + 4*r + mt (mt fast)
        const int n64 = (m0 + wy * 64) & 2047;
        const size_t bh64 = ((size_t)b * H_ + h) * 64;
        #pragma unroll
        for (int nt = 0; nt < 4; ++nt) {
            int d = nt * 16 + l16;
            #pragma unroll
            for (int r = 0; r < 4; ++r) {
                ushort4 v;
                v.x = f2bf(acc[0][nt][r] + bv[nt]);
                v.y = f2bf(acc[1][nt][r] + bv[nt]);
                v.z = f2bf(acc[2][nt][r] + bv[nt]);
                v.w = f2bf(acc[3][nt][r] + bv[nt]);
                *(ushort4*)&vt[(bh64 + d) * N_ + n64 + 16 * quad + 4 * r] = v;
            }
        }
    } else {
        unsigned short* dst = (three == 0) ? qb : kb;
        float sc = (three == 0) ? (0.125f * LOG2E) : 1.0f;
        #pragma unroll
        for (int mt = 0; mt < 4; ++mt)
            #pragma unroll
            for (int r = 0; r < 4; ++r) {
                int n = (m0 + wy * 64 + mt * 16 + quad * 4 + r) & 2047;
                size_t rowbase = (((size_t)b * H_ + h) * N_ + n) * D_;
                #pragma unroll
                for (int nt = 0; nt < 4; ++nt)
                    dst[rowbase + nt * 16 + l16] = f2bf((acc[mt][nt][r] + bv[nt]) * sc);
            }
    }
}

// ---------------- Flash attention: split-K x2, bias in MFMA ----------------
// New in this version:
//  - power-of-2 row strides + XOR slot swizzle (slot ^= row&7) on Ks/Vs/Ps
//    -> bank-uniform b128 reads/writes (was 5.77M conflict cycles/dispatch)
//  - register-staged async prefetch of next K/V tile + Pm ext (T14)
//  - defer-max rescale threshold 8 (T13), s_setprio around MFMA (T5)
// Ks row = 256B: slots 0..7 = K d-data, slots 8..15 = bias-ext region
//   (zero-inited once; per tile only 2 swizzled slots rewritten per row).
#define LDH 128   // Ks row stride in shorts (256 B, 16 slots of 16 B)
#define LDV 64    // Vs / Ps row stride in shorts (128 B, 8 slots)

__global__ __launch_bounds__(256) void attn_kernel(
    const unsigned short* __restrict__ qb, const unsigned short* __restrict__ kb,
    const unsigned short* __restrict__ vt,
    const float* __restrict__ Rm, const float* __restrict__ Pm,
    const float* __restrict__ ps_ptr,
    unsigned short* __restrict__ Opart, float* __restrict__ ml)
{
    __shared__ __align__(16) unsigned short Ks[64 * LDH]; // 16 KB
    __shared__ __align__(16) unsigned short Vs[64 * LDV]; // 8 KB
    __shared__ __align__(16) unsigned short Ps[64 * LDV]; // 8 KB

    const int bh = blockIdx.y;
    const int b = bh >> 2;
    const int i0 = blockIdx.x * 64;
    const int split = blockIdx.z;
    const int tid = threadIdx.x;
    const int wave = tid >> 6, lane = tid & 63;
    const int quad = lane >> 4, l16 = lane & 15;
    const int x7 = l16 & 7;
    const float ps = ps_ptr[0];

    const size_t base = (size_t)bh * N_ * D_;
    const unsigned short* qg = qb + base;
    const unsigned short* kg = kb + base;
    const unsigned short* vg = vt + base;   // rows of length N_

    // zero the ext half of Ks (slots 8..15, all rows) once: 512 uint4
    {
        const uint4 z = {0u, 0u, 0u, 0u};
        int u0 = tid, u1 = tid + 256;
        *(uint4*)&Ks[(u0 >> 3) * LDH + 64 + (u0 & 7) * 8] = z;
        *(uint4*)&Ks[(u1 >> 3) * LDH + 64 + (u1 & 7) * 8] = z;
    }

    // Q A-fragments (pre-scaled by 0.125*log2e)
    const int qrow = i0 + wave * 16 + l16;
    bf16x8 aq[3];
    #pragma unroll
    for (int ks = 0; ks < 2; ++ks)
        aq[ks] = ld_frag(&qg[(size_t)qrow * D_ + ks * 32 + quad * 8]);

    // A-side bias ext: a = ps*log2e*(R_b @ P_qrow), hi/lo split
    {
        float p0 = Pm[qrow * 3 + 0], p1 = Pm[qrow * 3 + 1], p2 = Pm[qrow * 3 + 2];
        float sc = ps * LOG2E;
        unsigned short ah[3], al[3];
        #pragma unroll
        for (int c = 0; c < 3; ++c) {
            float a = (Rm[b * 9 + c * 3 + 0] * p0 + Rm[b * 9 + c * 3 + 1] * p1
                     + Rm[b * 9 + c * 3 + 2] * p2) * sc;
            ah[c] = f2bf(a);
            al[c] = f2bf(a - bf2f(ah[c]));
        }
        bf16x8 e = (bf16x8){0,0,0,0,0,0,0,0};
        if (quad == 0) {
            e[0] = (short)ah[0]; e[1] = (short)ah[1]; e[2] = (short)ah[2];
            e[3] = (short)ah[0]; e[4] = (short)ah[1]; e[5] = (short)ah[2];
            e[6] = (short)al[0]; e[7] = (short)al[1];
        } else if (quad == 1) {
            e[0] = (short)al[2];
        }
        aq[2] = e;
    }

    const bf16x8 ones = (bf16x8){0x3F80,0x3F80,0x3F80,0x3F80,0x3F80,0x3F80,0x3F80,0x3F80};

    float m_run = -1e30f;
    f32x4 o_acc[4], lacc;
    #pragma unroll
    for (int t = 0; t < 4; ++t) o_acc[t] = (f32x4){0.f, 0.f, 0.f, 0.f};
    lacc = (f32x4){0.f, 0.f, 0.f, 0.f};

    const int jbeg = split * (N_ / 2);
    const int NT = (N_ / 2) / 64;

    // ---- register staging setup (async prefetch) ----
    const int r0 = tid >> 3, r1 = r0 + 32;   // staged rows per thread
    const int sl = tid & 7;                  // 16B slot within row
    const int so = sl * 8;                   // short offset in source row
    const int kw0 = r0 * LDH + ((sl ^ (r0 & 7)) * 8);
    const int kw1 = r1 * LDH + ((sl ^ (r1 & 7)) * 8);
    const int vw0 = r0 * LDV + ((sl ^ (r0 & 7)) * 8);
    const int vw1 = r1 * LDV + ((sl ^ (r1 & 7)) * 8);

    const unsigned short* kp0 = kg + (size_t)(jbeg + r0) * D_ + so;
    const unsigned short* kp1 = kg + (size_t)(jbeg + r1) * D_ + so;
    const unsigned short* vp0 = vg + (size_t)r0 * N_ + jbeg + so;
    const unsigned short* vp1 = vg + (size_t)r1 * N_ + jbeg + so;
    const float* pp = Pm + (size_t)(jbeg + tid) * 3;

    uint4 rk0, rk1, rv0, rv1;
    uint4 elo, ehi;

    auto LOAD = [&]() {
        rk0 = *(const uint4*)kp0; rk1 = *(const uint4*)kp1;
        rv0 = *(const uint4*)vp0; rv1 = *(const uint4*)vp1;
        if (tid < 64) {
            float p0 = pp[0], p1 = pp[1], p2 = pp[2];
            unsigned u0 = f2bf(p0), u1 = f2bf(p1), u2 = f2bf(p2);
            unsigned v0 = f2bf(p0 - bf2f((unsigned short)u0));
            unsigned v1 = f2bf(p1 - bf2f((unsigned short)u1));
            unsigned v2 = f2bf(p2 - bf2f((unsigned short)u2));
            elo.x = u0 | (u1 << 16); elo.y = u2 | (v0 << 16);
            elo.z = v1 | (v2 << 16); elo.w = u0 | (u1 << 16);
            ehi.x = u2; ehi.y = 0u; ehi.z = 0u; ehi.w = 0u;
        }
    };

    LOAD();   // prologue: tile 0 into registers

    for (int jt = 0; jt < NT; ++jt) {
        __syncthreads();   // prior tile fully read (also drains prefetch vmem)
        // regs -> LDS (swizzled)
        *(uint4*)&Ks[kw0] = rk0;
        *(uint4*)&Ks[kw1] = rk1;
        *(uint4*)&Vs[vw0] = rv0;
        *(uint4*)&Vs[vw1] = rv1;
        if (tid < 64) {
            *(uint4*)&Ks[tid * LDH + ((8 ^ (tid & 7)) * 8)] = elo;
            *(uint4*)&Ks[tid * LDH + ((9 ^ (tid & 7)) * 8)] = ehi;
        }
        __syncthreads();

        // issue next tile's global loads now; latency hides under QK+softmax+PV
        if (jt + 1 < NT) {
            kp0 += 64 * D_; kp1 += 64 * D_;
            vp0 += 64;      vp1 += 64;
            pp  += 64 * 3;
            LOAD();
        }

        // S (log2-domain logits incl. bias): 3 k-steps x 4 col-tiles
        f32x4 s[4];
        __builtin_amdgcn_s_setprio(1);
        #pragma unroll
        for (int t = 0; t < 4; ++t) {
            f32x4 c = {0.f, 0.f, 0.f, 0.f};
            const int rb = (l16 + 16 * t) * LDH;
            #pragma unroll
            for (int ks = 0; ks < 3; ++ks) {
                bf16x8 bk = ld_frag(&Ks[rb + (((ks * 4 + quad) ^ x7) * 8)]);
                c = __builtin_amdgcn_mfma_f32_16x16x32_bf16(aq[ks], bk, c, 0, 0, 0);
            }
            s[t] = c;
        }
        __builtin_amdgcn_s_setprio(0);

        // strip max over the wave's 16x64 logits
        float mx = s[0][0];
        #pragma unroll
        for (int t = 0; t < 4; ++t)
            #pragma unroll
            for (int r = 0; r < 4; ++r)
                mx = fmaxf(mx, s[t][r]);
        #pragma unroll
        for (int off = 1; off < 64; off <<= 1)
            mx = fmaxf(mx, __shfl_xor(mx, off));

        // defer-max: only rescale when the max grew by > 8 (P bounded by 2^8)
        if (mx > m_run + 8.0f) {
            const float alpha = exp2f(m_run - mx);
            #pragma unroll
            for (int t = 0; t < 4; ++t)
                #pragma unroll
                for (int r = 0; r < 4; ++r)
                    o_acc[t][r] *= alpha;
            #pragma unroll
            for (int r = 0; r < 4; ++r) lacc[r] *= alpha;
            m_run = mx;
        }

        // p = exp2(lg - m_run); pack into Ps at perm position 4*l16 + t
        #pragma unroll
        for (int r = 0; r < 4; ++r) {
            float p0 = exp2f(s[0][r] - m_run), p1 = exp2f(s[1][r] - m_run);
            float p2 = exp2f(s[2][r] - m_run), p3 = exp2f(s[3][r] - m_run);
            uint2 w;
            w.x = pack2(p0, p1);
            w.y = pack2(p2, p3);
            const int prow = quad * 4 + r;
            *(uint2*)&Ps[(wave * 16 + prow) * LDV
                         + (((l16 >> 1) ^ (prow & 7)) * 8) + (l16 & 1) * 4] = w;
        }

        // O += P V; l += P . 1 (ones-MFMA)
        __builtin_amdgcn_s_setprio(1);
        #pragma unroll
        for (int ks = 0; ks < 2; ++ks) {
            bf16x8 ap = ld_frag(&Ps[(wave * 16 + l16) * LDV
                                    + (((ks * 4 + quad) ^ x7) * 8)]);
            #pragma unroll
            for (int t = 0; t < 4; ++t) {
                bf16x8 bv = ld_frag(&Vs[(l16 + 16 * t) * LDV
                                        + (((ks * 4 + quad) ^ x7) * 8)]);
                o_acc[t] = __builtin_amdgcn_mfma_f32_16x16x32_bf16(ap, bv, o_acc[t], 0, 0, 0);
            }
            lacc = __builtin_amdgcn_mfma_f32_16x16x32_bf16(ap, ones, lacc, 0, 0, 0);
        }
        __builtin_amdgcn_s_setprio(0);
    }

    // store unnormalized partial O (bf16) + (m,l) per row
    const size_t pbase = (size_t)(split * 16 + bh) * N_;
    #pragma unroll
    for (int r = 0; r < 4; ++r) {
        int row = i0 + wave * 16 + quad * 4 + r;
        #pragma unroll
        for (int t = 0; t < 4; ++t)
            Opart[(pbase + row) * D_ + l16 + 16 * t] = f2bf(o_acc[t][r]);
        if (l16 == 0) {
            float2* mlp = (float2*)ml;
            mlp[pbase + row] = make_float2(m_run, lacc[r]);
        }
    }
}

// ---------------- Output projection: fused 2-way merge, hoisted weights ----------
// 64x64 tile, 4 waves on M; bf16 weights from cvt prepass.
__global__ __launch_bounds__(256) void proj_gemm(
    const unsigned short* __restrict__ Opart, const float* __restrict__ ml,
    const unsigned short* __restrict__ wb, const float* __restrict__ bias,
    float* __restrict__ out)
{
    __shared__ __align__(16) unsigned short As[64 * 40];
    __shared__ __align__(16) unsigned short Bs[64 * 40];
    const int m0 = blockIdx.x * 64, o0 = blockIdx.y * 64;
    const int tid = threadIdx.x;
    const int wave = tid >> 6, lane = tid & 63, quad = lane >> 4, l16 = lane & 15;
    const float2* mlp = (const float2*)ml;

    const int srow = tid >> 2, scb = (tid & 3) * 8;
    const int sm = m0 + srow, sb = sm >> 11, sn = sm & 2047;

    // hoist 2-way merge weights per h
    float w1h[4], w2h[4];
    #pragma unroll
    for (int h = 0; h < 4; ++h) {
        size_t r1 = (size_t)(sb * 4 + h) * N_ + sn;
        float2 ml1 = mlp[r1], ml2 = mlp[r1 + 16 * N_];
        float mm = fmaxf(ml1.x, ml2.x);
        float w1 = exp2f(ml1.x - mm), w2 = exp2f(ml2.x - mm);
        float inv = 1.f / (ml1.y * w1 + ml2.y * w2);
        w1h[h] = w1 * inv; w2h[h] = w2 * inv;
    }

    f32x4 acc[4];
    #pragma unroll
    for (int j = 0; j < 4; ++j) acc[j] = (f32x4){0.f, 0.f, 0.f, 0.f};

    for (int k0 = 0; k0 < 256; k0 += 32) {
        const int h = k0 >> 6;
        const int d0 = (k0 & 63) + scb;
        __syncthreads();
        {   // A: 2-way merge -> bf16; B: bf16 copy
            size_t r1 = (size_t)(sb * 4 + h) * N_ + sn;
            union { uint4 u; unsigned short s[8]; } a1, a2;
            a1.u = *(const uint4*)&Opart[r1 * D_ + d0];
            a2.u = *(const uint4*)&Opart[(r1 + 16 * N_) * D_ + d0];
            float w1 = w1h[h], w2 = w2h[h];
            uint4 mv;
            unsigned* mp = (unsigned*)&mv;
            #pragma unroll
            for (int j = 0; j < 4; ++j)
                mp[j] = pack2(bf2f(a1.s[2*j]) * w1 + bf2f(a2.s[2*j]) * w2,
                              bf2f(a1.s[2*j+1]) * w1 + bf2f(a2.s[2*j+1]) * w2);
            *(uint4*)&As[srow * 40 + scb] = mv;
            *(uint4*)&Bs[srow * 40 + scb] = *(const uint4*)&wb[(size_t)(o0 + srow) * 256 + k0 + scb];
        }
        __syncthreads();
        bf16x8 a = ld_frag(&As[(wave * 16 + l16) * 40 + quad * 8]);
        #pragma unroll
        for (int nt = 0; nt < 4; ++nt) {
            bf16x8 b = ld_frag(&Bs[(nt * 16 + l16) * 40 + quad * 8]);
            acc[nt] = __builtin_amdgcn_mfma_f32_16x16x32_bf16(a, b, acc[nt], 0, 0, 0);
        }
    }

    float bv[4];
    #pragma unroll
    for (int nt = 0; nt < 4; ++nt) bv[nt] = bias[o0 + nt * 16 + l16];
    #pragma unroll
    for (int r = 0; r < 4; ++r) {
        int m = m0 + wave * 16 + quad * 4 + r;
        #pragma unroll
        for (int nt = 0; nt < 4; ++nt)
            out[(size_t)m * 256 + o0 + nt * 16 + l16] = acc[nt][r] + bv[nt];
    }
}

extern "C" void kernel_launch(void* const* d_in, const int* in_sizes, int n_in,
                              void* d_out, int out_size, void* d_ws, size_t ws_size,
                              hipStream_t stream) {
    const float* x       = (const float*)d_in[0];
    const float* Rm      = (const float*)d_in[1];
    const float* Pm      = (const float*)d_in[2];
    const float* qkv_w   = (const float*)d_in[3];
    const float* qkv_b   = (const float*)d_in[4];
    const float* proj_w  = (const float*)d_in[5];
    const float* proj_b  = (const float*)d_in[6];
    const float* pos_scl = (const float*)d_in[7];
    float* out = (float*)d_out;

    const size_t NE = (size_t)B_ * H_ * N_ * D_;   // 2,097,152
    unsigned short* xb    = (unsigned short*)d_ws; // 4 MB
    unsigned short* wqb   = xb   + NE;             // 768*256
    unsigned short* wpb   = wqb  + 768 * 256;      // 256*256
    unsigned short* qb    = wpb  + 256 * 256;      // 4 MB each
    unsigned short* kb    = qb   + NE;
    unsigned short* vtb   = kb   + NE;
    unsigned short* opart = vtb  + NE;             // 2*NE = 8 MB
    float*          mlb   = (float*)(opart + 2 * NE);  // 2*16*2048 float2 = 512 KB

    cvt_kernel<<<1152, 256, 0, stream>>>(x, qkv_w, proj_w, xb, wqb, wpb);
    qkv_gemm<<<dim3(64, 6), 256, 0, stream>>>(xb, wqb, qkv_b, qb, kb, vtb);
    attn_kernel<<<dim3(32, 16, 2), 256, 0, stream>>>(qb, kb, vtb, Rm, Pm, pos_scl, opart, mlb);
    proj_gemm<<<dim3(128, 4), 256, 0, stream>>>(opart, mlb, wpb, proj_b, out);
}

// Round 2
// 145.243 us; speedup vs baseline: 1.0671x; 1.0671x over previous
//
#include <hip/hip_runtime.h>
#include <hip/hip_bf16.h>

#define B_ 4
#define N_ 2048
#define C_ 256
#define H_ 4
#define D_ 64

typedef __attribute__((ext_vector_type(8))) short bf16x8;
typedef __attribute__((ext_vector_type(4))) float f32x4;

#define LOG2E 1.4426950408889634f

// f32 -> bf16 round-to-nearest-even (scalar)
static __device__ inline unsigned short f2bf(float f) {
    unsigned u = __builtin_bit_cast(unsigned, f);
    unsigned r = (u + 0x7fffu + ((u >> 16) & 1u)) >> 16;
    return (unsigned short)r;
}
static __device__ inline float bf2f(unsigned short h) {
    unsigned u = ((unsigned)h) << 16;
    return __builtin_bit_cast(float, u);
}
// packed pair f32 -> bf16x2
static __device__ inline unsigned pack2(float a, float b) {
    __hip_bfloat162 h = __float22bfloat162_rn(make_float2(a, b));
    unsigned u;
    __builtin_memcpy(&u, &h, 4);
    return u;
}
static __device__ inline bf16x8 ld_frag(const unsigned short* p) {
    return __builtin_bit_cast(bf16x8, *(const uint4*)p);
}
// async global->LDS DMA, 16B per lane, dest = ldsbase + lane*16
static __device__ inline void gload_lds16(const unsigned short* g, unsigned short* l) {
    __builtin_amdgcn_global_load_lds(
        (const __attribute__((address_space(1))) unsigned int*)(g),
        (__attribute__((address_space(3))) unsigned int*)(l),
        16, 0, 0);
}

// ---------------- cvt prepass: x / qkv_w / proj_w -> bf16; Pm -> ext table ----
// ext row (16 shorts) per key n: [ph0,ph1,ph2,pl0,pl1,pl2,ph0,ph1 | ph2,0,..,0]
__global__ __launch_bounds__(256) void cvt_kernel(
    const float* __restrict__ x, const float* __restrict__ qkv_w,
    const float* __restrict__ proj_w, const float* __restrict__ Pm,
    unsigned short* __restrict__ xb, unsigned short* __restrict__ wqb,
    unsigned short* __restrict__ wpb, unsigned short* __restrict__ eb)
{
    const int bid = blockIdx.x, tid = threadIdx.x;
    if (bid >= 1152) {
        const int n = (bid - 1152) * 256 + tid;
        const float* pp = Pm + n * 3;
        float p0 = pp[0], p1 = pp[1], p2 = pp[2];
        unsigned u0 = f2bf(p0), u1 = f2bf(p1), u2 = f2bf(p2);
        unsigned v0 = f2bf(p0 - bf2f((unsigned short)u0));
        unsigned v1 = f2bf(p1 - bf2f((unsigned short)u1));
        unsigned v2 = f2bf(p2 - bf2f((unsigned short)u2));
        uint4 lo, hi;
        lo.x = u0 | (u1 << 16); lo.y = u2 | (v0 << 16);
        lo.z = v1 | (v2 << 16); lo.w = u0 | (u1 << 16);
        hi.x = u2; hi.y = 0u; hi.z = 0u; hi.w = 0u;
        *(uint4*)&eb[n * 16 + 0] = lo;
        *(uint4*)&eb[n * 16 + 8] = hi;
        return;
    }
    const float* s; unsigned short* d; int i;
    if (bid < 1024)      { s = x;      d = xb;  i = (bid * 256 + tid) * 8; }
    else if (bid < 1120) { s = qkv_w;  d = wqb; i = ((bid - 1024) * 256 + tid) * 8; }
    else                 { s = proj_w; d = wpb; i = ((bid - 1120) * 256 + tid) * 8; }
    float4 a = *(const float4*)(s + i);
    float4 b = *(const float4*)(s + i + 4);
    uint4 u;
    u.x = pack2(a.x, a.y); u.y = pack2(a.z, a.w);
    u.z = pack2(b.x, b.y); u.w = pack2(b.z, b.w);
    *(uint4*)(d + i) = u;
}

// ---------------- QKV GEMM: bf16, 128x128 tile, 4 waves 2x2, BK=32 ----------
// Q pre-scaled by 0.125*log2e. V written transposed+permuted:
// vt[bh][d][n_perm], perm within 64-block: p = 4*(n&15)+((n>>4)&3).
__global__ __launch_bounds__(256) void qkv_gemm(
    const unsigned short* __restrict__ xb, const unsigned short* __restrict__ wb,
    const float* __restrict__ bias, unsigned short* __restrict__ qb,
    unsigned short* __restrict__ kb, unsigned short* __restrict__ vt)
{
    __shared__ __align__(16) unsigned short As[128 * 40];
    __shared__ __align__(16) unsigned short Bs[128 * 40];
    const int m0 = blockIdx.x * 128, o0 = blockIdx.y * 128;
    const int tid = threadIdx.x;
    const int wave = tid >> 6, lane = tid & 63, quad = lane >> 4, l16 = lane & 15;
    const int wy = wave >> 1, wx = wave & 1;

    f32x4 acc[4][4];
    #pragma unroll
    for (int i = 0; i < 4; ++i)
        #pragma unroll
        for (int j = 0; j < 4; ++j) acc[i][j] = (f32x4){0.f, 0.f, 0.f, 0.f};

    const int srow = tid >> 1, soff = (tid & 1) * 16;   // 128 rows x 32 cols staging

    for (int k0 = 0; k0 < 256; k0 += 32) {
        __syncthreads();
        {
            const unsigned short* sa = &xb[(size_t)(m0 + srow) * 256 + k0 + soff];
            const unsigned short* sb = &wb[(size_t)(o0 + srow) * 256 + k0 + soff];
            *(uint4*)&As[srow * 40 + soff + 0] = *(const uint4*)(sa + 0);
            *(uint4*)&As[srow * 40 + soff + 8] = *(const uint4*)(sa + 8);
            *(uint4*)&Bs[srow * 40 + soff + 0] = *(const uint4*)(sb + 0);
            *(uint4*)&Bs[srow * 40 + soff + 8] = *(const uint4*)(sb + 8);
        }
        __syncthreads();
        bf16x8 a[4], b[4];
        #pragma unroll
        for (int mt = 0; mt < 4; ++mt) a[mt] = ld_frag(&As[(wy * 64 + mt * 16 + l16) * 40 + quad * 8]);
        #pragma unroll
        for (int nt = 0; nt < 4; ++nt) b[nt] = ld_frag(&Bs[(wx * 64 + nt * 16 + l16) * 40 + quad * 8]);
        #pragma unroll
        for (int mt = 0; mt < 4; ++mt)
            #pragma unroll
            for (int nt = 0; nt < 4; ++nt)
                acc[mt][nt] = __builtin_amdgcn_mfma_f32_16x16x32_bf16(a[mt], b[nt], acc[mt][nt], 0, 0, 0);
    }

    const int sec = o0 + wx * 64;            // this wave's 64 output cols
    const int three = sec >> 8;
    const int h = (sec >> 6) & 3;
    const int b = m0 >> 11;
    float bv[4];
    #pragma unroll
    for (int nt = 0; nt < 4; ++nt) bv[nt] = bias[sec + nt * 16 + l16];

    if (three == 2) {
        // V: n = m0 + wy*64 + mt*16 + quad*4 + r; p = 16*quad + 4*r + mt (mt fast)
        const int n64 = (m0 + wy * 64) & 2047;
        const size_t bh64 = ((size_t)b * H_ + h) * 64;
        #pragma unroll
        for (int nt = 0; nt < 4; ++nt) {
            int d = nt * 16 + l16;
            #pragma unroll
            for (int r = 0; r < 4; ++r) {
                ushort4 v;
                v.x = f2bf(acc[0][nt][r] + bv[nt]);
                v.y = f2bf(acc[1][nt][r] + bv[nt]);
                v.z = f2bf(acc[2][nt][r] + bv[nt]);
                v.w = f2bf(acc[3][nt][r] + bv[nt]);
                *(ushort4*)&vt[(bh64 + d) * N_ + n64 + 16 * quad + 4 * r] = v;
            }
        }
    } else {
        unsigned short* dst = (three == 0) ? qb : kb;
        float sc = (three == 0) ? (0.125f * LOG2E) : 1.0f;
        #pragma unroll
        for (int mt = 0; mt < 4; ++mt)
            #pragma unroll
            for (int r = 0; r < 4; ++r) {
                int n = (m0 + wy * 64 + mt * 16 + quad * 4 + r) & 2047;
                size_t rowbase = (((size_t)b * H_ + h) * N_ + n) * D_;
                #pragma unroll
                for (int nt = 0; nt < 4; ++nt)
                    dst[rowbase + nt * 16 + l16] = f2bf((acc[mt][nt][r] + bv[nt]) * sc);
            }
    }
}

// ---------------- Flash attention: split-K x2, bias in MFMA -------------------
// DMA pipeline: global_load_lds into double-buffered Ks/Vs (linear dest,
// pre-swizzled global source: LDS[row][s] = src[row][s ^ (row&7)]); one
// barrier/iter (implicit vmcnt(0) drain = arrival sync). Ext (bias B-side)
// from precomputed eb table straight into registers. 40KB LDS -> 4 blocks/CU.
#define LDK 64   // Ks/Vs/Ps row stride in shorts (128 B, 8 slots of 16 B)

__global__ __launch_bounds__(256) void attn_kernel(
    const unsigned short* __restrict__ qb, const unsigned short* __restrict__ kb,
    const unsigned short* __restrict__ vt, const unsigned short* __restrict__ eb,
    const float* __restrict__ Rm, const float* __restrict__ Pm,
    const float* __restrict__ ps_ptr,
    unsigned short* __restrict__ Opart, float* __restrict__ ml)
{
    __shared__ __align__(16) unsigned short Ks[2][64 * LDK]; // 16 KB
    __shared__ __align__(16) unsigned short Vs[2][64 * LDK]; // 16 KB
    __shared__ __align__(16) unsigned short Ps[64 * LDK];    // 8 KB

    const int bh = blockIdx.y;
    const int b = bh >> 2;
    const int i0 = blockIdx.x * 64;
    const int split = blockIdx.z;
    const int tid = threadIdx.x;
    const int wave = tid >> 6, lane = tid & 63;
    const int quad = lane >> 4, l16 = lane & 15;
    const int x7 = l16 & 7;
    const float ps = ps_ptr[0];

    const size_t base = (size_t)bh * N_ * D_;
    const unsigned short* qg = qb + base;
    const unsigned short* kg = kb + base;
    const unsigned short* vg = vt + base;   // rows of length N_

    const int jbeg = split * (N_ / 2);
    const int NT = (N_ / 2) / 64;

    // ---- DMA source pointers (pre-swizzled), advanced per tile ----
    const int rl = lane >> 3, sl = lane & 7;          // 8 rows x 8 slots per issue
    const int swz = (sl ^ rl) * 8;
    const unsigned short* kq = kg + (size_t)(jbeg + wave * 16 + rl) * D_ + swz;
    const unsigned short* vq = vg + (size_t)(wave * 16 + rl) * N_ + jbeg + swz;
    const unsigned short* ep = eb + (size_t)(jbeg + l16) * 16 + (quad & 1) * 8;

    auto ISSUE = [&](int nb) {
        unsigned short* kd = &Ks[nb][(wave * 16) * LDK];
        unsigned short* vd = &Vs[nb][(wave * 16) * LDK];
        gload_lds16(kq,           kd);
        gload_lds16(kq + 8 * D_,  kd + 8 * LDK);
        gload_lds16(vq,           vd);
        gload_lds16(vq + 8 * N_,  vd + 8 * LDK);
    };

    // prologue: tile 0 DMA + ext frags
    ISSUE(0);
    kq += 64 * D_; vq += 64;
    bf16x8 ereg[4];
    #pragma unroll
    for (int t = 0; t < 4; ++t) ereg[t] = ld_frag(ep + t * 256);
    ep += 64 * 16;

    // Q A-fragments (pre-scaled by 0.125*log2e)
    const int qrow = i0 + wave * 16 + l16;
    bf16x8 aq[3];
    #pragma unroll
    for (int ks = 0; ks < 2; ++ks)
        aq[ks] = ld_frag(&qg[(size_t)qrow * D_ + ks * 32 + quad * 8]);

    // A-side bias ext: a = ps*log2e*(R_b @ P_qrow), hi/lo split
    {
        float p0 = Pm[qrow * 3 + 0], p1 = Pm[qrow * 3 + 1], p2 = Pm[qrow * 3 + 2];
        float sc = ps * LOG2E;
        unsigned short ah[3], al[3];
        #pragma unroll
        for (int c = 0; c < 3; ++c) {
            float a = (Rm[b * 9 + c * 3 + 0] * p0 + Rm[b * 9 + c * 3 + 1] * p1
                     + Rm[b * 9 + c * 3 + 2] * p2) * sc;
            ah[c] = f2bf(a);
            al[c] = f2bf(a - bf2f(ah[c]));
        }
        bf16x8 e = (bf16x8){0,0,0,0,0,0,0,0};
        if (quad == 0) {
            e[0] = (short)ah[0]; e[1] = (short)ah[1]; e[2] = (short)ah[2];
            e[3] = (short)ah[0]; e[4] = (short)ah[1]; e[5] = (short)ah[2];
            e[6] = (short)al[0]; e[7] = (short)al[1];
        } else if (quad == 1) {
            e[0] = (short)al[2];
        }
        aq[2] = e;
    }

    const bf16x8 ones = (bf16x8){0x3F80,0x3F80,0x3F80,0x3F80,0x3F80,0x3F80,0x3F80,0x3F80};

    float m_run = -1e30f;
    f32x4 o_acc[4], lacc;
    #pragma unroll
    for (int t = 0; t < 4; ++t) o_acc[t] = (f32x4){0.f, 0.f, 0.f, 0.f};
    lacc = (f32x4){0.f, 0.f, 0.f, 0.f};

    for (int jt = 0; jt < NT; ++jt) {
        const int cur = jt & 1;
        // arrival of tile jt's DMA + everyone done reading buffer cur^1
        asm volatile("s_waitcnt vmcnt(0)" ::: "memory");
        __syncthreads();
        if (jt + 1 < NT) {          // issue next tile into freed buffer
            ISSUE(cur ^ 1);
            kq += 64 * D_; vq += 64;
        }

        // S (log2-domain logits incl. bias): (2 K-steps from LDS + ext) x 4 tiles
        f32x4 s[4];
        __builtin_amdgcn_s_setprio(1);
        #pragma unroll
        for (int t = 0; t < 4; ++t) {
            const int rb = (l16 + 16 * t) * LDK;
            f32x4 c = {0.f, 0.f, 0.f, 0.f};
            #pragma unroll
            for (int ks = 0; ks < 2; ++ks) {
                bf16x8 bk = ld_frag(&Ks[cur][rb + (((ks * 4 + quad) ^ x7) * 8)]);
                c = __builtin_amdgcn_mfma_f32_16x16x32_bf16(aq[ks], bk, c, 0, 0, 0);
            }
            c = __builtin_amdgcn_mfma_f32_16x16x32_bf16(aq[2], ereg[t], c, 0, 0, 0);
            s[t] = c;
        }
        __builtin_amdgcn_s_setprio(0);

        // prefetch next tile's ext frags (consumed next iteration)
        if (jt + 1 < NT) {
            #pragma unroll
            for (int t = 0; t < 4; ++t) ereg[t] = ld_frag(ep + t * 256);
            ep += 64 * 16;
        }

        // per-quad (4-row-group) max over this tile's 64 keys
        float mx = s[0][0];
        #pragma unroll
        for (int t = 0; t < 4; ++t)
            #pragma unroll
            for (int r = 0; r < 4; ++r)
                mx = fmaxf(mx, s[t][r]);
        #pragma unroll
        for (int off = 1; off < 16; off <<= 1)
            mx = fmaxf(mx, __shfl_xor(mx, off));

        // defer-max: rescale only when some quad's max grew by > 8
        if (__any(mx > m_run + 8.0f)) {
            float mnew = fmaxf(m_run, mx);
            float alpha = exp2f(m_run - mnew);
            #pragma unroll
            for (int t = 0; t < 4; ++t)
                #pragma unroll
                for (int r = 0; r < 4; ++r)
                    o_acc[t][r] *= alpha;
            #pragma unroll
            for (int r = 0; r < 4; ++r) lacc[r] *= alpha;
            m_run = mnew;
        }

        // p = exp2(lg - m_run); pack into Ps at perm position 4*l16 + t
        #pragma unroll
        for (int r = 0; r < 4; ++r) {
            float p0 = exp2f(s[0][r] - m_run), p1 = exp2f(s[1][r] - m_run);
            float p2 = exp2f(s[2][r] - m_run), p3 = exp2f(s[3][r] - m_run);
            uint2 w;
            w.x = pack2(p0, p1);
            w.y = pack2(p2, p3);
            const int prow = quad * 4 + r;
            *(uint2*)&Ps[(wave * 16 + prow) * LDK
                         + (((l16 >> 1) ^ (prow & 7)) * 8) + (l16 & 1) * 4] = w;
        }

        // O += P V; l += P . 1 (ones-MFMA)
        __builtin_amdgcn_s_setprio(1);
        #pragma unroll
        for (int ks = 0; ks < 2; ++ks) {
            bf16x8 ap = ld_frag(&Ps[(wave * 16 + l16) * LDK
                                    + (((ks * 4 + quad) ^ x7) * 8)]);
            #pragma unroll
            for (int t = 0; t < 4; ++t) {
                bf16x8 bv = ld_frag(&Vs[cur][(l16 + 16 * t) * LDK
                                             + (((ks * 4 + quad) ^ x7) * 8)]);
                o_acc[t] = __builtin_amdgcn_mfma_f32_16x16x32_bf16(ap, bv, o_acc[t], 0, 0, 0);
            }
            lacc = __builtin_amdgcn_mfma_f32_16x16x32_bf16(ap, ones, lacc, 0, 0, 0);
        }
        __builtin_amdgcn_s_setprio(0);
    }

    // store unnormalized partial O (bf16) + (m,l) per row
    const size_t pbase = (size_t)(split * 16 + bh) * N_;
    #pragma unroll
    for (int r = 0; r < 4; ++r) {
        int row = i0 + wave * 16 + quad * 4 + r;
        #pragma unroll
        for (int t = 0; t < 4; ++t)
            Opart[(pbase + row) * D_ + l16 + 16 * t] = f2bf(o_acc[t][r]);
        if (l16 == 0) {
            float2* mlp = (float2*)ml;
            mlp[pbase + row] = make_float2(m_run, lacc[r]);
        }
    }
}

// ---------------- Output projection: fused 2-way merge, hoisted weights ----------
// 64x64 tile, 4 waves on M; bf16 weights from cvt prepass.
__global__ __launch_bounds__(256) void proj_gemm(
    const unsigned short* __restrict__ Opart, const float* __restrict__ ml,
    const unsigned short* __restrict__ wb, const float* __restrict__ bias,
    float* __restrict__ out)
{
    __shared__ __align__(16) unsigned short As[64 * 40];
    __shared__ __align__(16) unsigned short Bs[64 * 40];
    const int m0 = blockIdx.x * 64, o0 = blockIdx.y * 64;
    const int tid = threadIdx.x;
    const int wave = tid >> 6, lane = tid & 63, quad = lane >> 4, l16 = lane & 15;
    const float2* mlp = (const float2*)ml;

    const int srow = tid >> 2, scb = (tid & 3) * 8;
    const int sm = m0 + srow, sb = sm >> 11, sn = sm & 2047;

    // hoist 2-way merge weights per h
    float w1h[4], w2h[4];
    #pragma unroll
    for (int h = 0; h < 4; ++h) {
        size_t r1 = (size_t)(sb * 4 + h) * N_ + sn;
        float2 ml1 = mlp[r1], ml2 = mlp[r1 + 16 * N_];
        float mm = fmaxf(ml1.x, ml2.x);
        float w1 = exp2f(ml1.x - mm), w2 = exp2f(ml2.x - mm);
        float inv = 1.f / (ml1.y * w1 + ml2.y * w2);
        w1h[h] = w1 * inv; w2h[h] = w2 * inv;
    }

    f32x4 acc[4];
    #pragma unroll
    for (int j = 0; j < 4; ++j) acc[j] = (f32x4){0.f, 0.f, 0.f, 0.f};

    for (int k0 = 0; k0 < 256; k0 += 32) {
        const int h = k0 >> 6;
        const int d0 = (k0 & 63) + scb;
        __syncthreads();
        {   // A: 2-way merge -> bf16; B: bf16 copy
            size_t r1 = (size_t)(sb * 4 + h) * N_ + sn;
            union { uint4 u; unsigned short s[8]; } a1, a2;
            a1.u = *(const uint4*)&Opart[r1 * D_ + d0];
            a2.u = *(const uint4*)&Opart[(r1 + 16 * N_) * D_ + d0];
            float w1 = w1h[h], w2 = w2h[h];
            uint4 mv;
            unsigned* mp = (unsigned*)&mv;
            #pragma unroll
            for (int j = 0; j < 4; ++j)
                mp[j] = pack2(bf2f(a1.s[2*j]) * w1 + bf2f(a2.s[2*j]) * w2,
                              bf2f(a1.s[2*j+1]) * w1 + bf2f(a2.s[2*j+1]) * w2);
            *(uint4*)&As[srow * 40 + scb] = mv;
            *(uint4*)&Bs[srow * 40 + scb] = *(const uint4*)&wb[(size_t)(o0 + srow) * 256 + k0 + scb];
        }
        __syncthreads();
        bf16x8 a = ld_frag(&As[(wave * 16 + l16) * 40 + quad * 8]);
        #pragma unroll
        for (int nt = 0; nt < 4; ++nt) {
            bf16x8 b = ld_frag(&Bs[(nt * 16 + l16) * 40 + quad * 8]);
            acc[nt] = __builtin_amdgcn_mfma_f32_16x16x32_bf16(a, b, acc[nt], 0, 0, 0);
        }
    }

    float bv[4];
    #pragma unroll
    for (int nt = 0; nt < 4; ++nt) bv[nt] = bias[o0 + nt * 16 + l16];
    #pragma unroll
    for (int r = 0; r < 4; ++r) {
        int m = m0 + wave * 16 + quad * 4 + r;
        #pragma unroll
        for (int nt = 0; nt < 4; ++nt)
            out[(size_t)m * 256 + o0 + nt * 16 + l16] = acc[nt][r] + bv[nt];
    }
}

extern "C" void kernel_launch(void* const* d_in, const int* in_sizes, int n_in,
                              void* d_out, int out_size, void* d_ws, size_t ws_size,
                              hipStream_t stream) {
    const float* x       = (const float*)d_in[0];
    const float* Rm      = (const float*)d_in[1];
    const float* Pm      = (const float*)d_in[2];
    const float* qkv_w   = (const float*)d_in[3];
    const float* qkv_b   = (const float*)d_in[4];
    const float* proj_w  = (const float*)d_in[5];
    const float* proj_b  = (const float*)d_in[6];
    const float* pos_scl = (const float*)d_in[7];
    float* out = (float*)d_out;

    const size_t NE = (size_t)B_ * H_ * N_ * D_;   // 2,097,152
    unsigned short* xb    = (unsigned short*)d_ws; // 4 MB
    unsigned short* wqb   = xb   + NE;             // 768*256
    unsigned short* wpb   = wqb  + 768 * 256;      // 256*256
    unsigned short* qb    = wpb  + 256 * 256;      // 4 MB each
    unsigned short* kb    = qb   + NE;
    unsigned short* vtb   = kb   + NE;
    unsigned short* opart = vtb  + NE;             // 2*NE = 8 MB
    float*          mlb   = (float*)(opart + 2 * NE);  // 2*16*2048 float2 = 512 KB
    unsigned short* eb    = (unsigned short*)(mlb + 2 * 16 * N_ * 2); // 64 KB ext table

    cvt_kernel<<<1160, 256, 0, stream>>>(x, qkv_w, proj_w, Pm, xb, wqb, wpb, eb);
    qkv_gemm<<<dim3(64, 6), 256, 0, stream>>>(xb, wqb, qkv_b, qb, kb, vtb);
    attn_kernel<<<dim3(32, 16, 2), 256, 0, stream>>>(qb, kb, vtb, eb, Rm, Pm, pos_scl, opart, mlb);
    proj_gemm<<<dim3(128, 4), 256, 0, stream>>>(opart, mlb, wpb, proj_b, out);
}

// Round 3
// 144.549 us; speedup vs baseline: 1.0723x; 1.0048x over previous
//
#include <hip/hip_runtime.h>
#include <hip/hip_bf16.h>

#define B_ 4
#define N_ 2048
#define C_ 256
#define H_ 4
#define D_ 64

typedef __attribute__((ext_vector_type(8))) short bf16x8;
typedef __attribute__((ext_vector_type(4))) float f32x4;

#define LOG2E 1.4426950408889634f

// f32 -> bf16 round-to-nearest-even (scalar)
static __device__ inline unsigned short f2bf(float f) {
    unsigned u = __builtin_bit_cast(unsigned, f);
    unsigned r = (u + 0x7fffu + ((u >> 16) & 1u)) >> 16;
    return (unsigned short)r;
}
static __device__ inline float bf2f(unsigned short h) {
    unsigned u = ((unsigned)h) << 16;
    return __builtin_bit_cast(float, u);
}
// packed pair f32 -> bf16x2
static __device__ inline unsigned pack2(float a, float b) {
    __hip_bfloat162 h = __float22bfloat162_rn(make_float2(a, b));
    unsigned u;
    __builtin_memcpy(&u, &h, 4);
    return u;
}
static __device__ inline bf16x8 ld_frag(const unsigned short* p) {
    return __builtin_bit_cast(bf16x8, *(const uint4*)p);
}
// async global->LDS DMA, 16B per lane, dest = ldsbase + lane*16
static __device__ inline void gload_lds16(const unsigned short* g, unsigned short* l) {
    __builtin_amdgcn_global_load_lds(
        (const __attribute__((address_space(1))) unsigned int*)(g),
        (__attribute__((address_space(3))) unsigned int*)(l),
        16, 0, 0);
}
// fmax with a DPP-permuted copy (VALU-latency cross-lane, 16-lane row scope)
template<int CTRL>
static __device__ inline float fmax_dpp(float x) {
    int yi = __builtin_amdgcn_update_dpp(0, __builtin_bit_cast(int, x),
                                         CTRL, 0xf, 0xf, true);
    return fmaxf(x, __builtin_bit_cast(float, yi));
}

// ---------------- QKV GEMM: f32 in, bf16 staged, 128x128 tile, BK=32 --------
// Converts x/qkv_w to bf16 during staging (cvt prepass eliminated).
// Q pre-scaled by 0.125*log2e. V written transposed+permuted:
// vt[bh][d][n_perm], perm within 64-block: p = 4*(n&15)+((n>>4)&3).
// Blocks (y==0, x<8) also build the eb ext table from Pm.
__global__ __launch_bounds__(256) void qkv_gemm(
    const float* __restrict__ x, const float* __restrict__ qw,
    const float* __restrict__ bias, const float* __restrict__ Pm,
    unsigned short* __restrict__ qb, unsigned short* __restrict__ kb,
    unsigned short* __restrict__ vt, unsigned short* __restrict__ eb)
{
    __shared__ __align__(16) unsigned short As[128 * 40];
    __shared__ __align__(16) unsigned short Bs[128 * 40];
    const int m0 = blockIdx.x * 128, o0 = blockIdx.y * 128;
    const int tid = threadIdx.x;
    const int wave = tid >> 6, lane = tid & 63, quad = lane >> 4, l16 = lane & 15;
    const int wy = wave >> 1, wx = wave & 1;

    // ext table build (b-independent bias B-side), 8 blocks cover 2048 keys
    if (blockIdx.y == 0 && blockIdx.x < 8) {
        const int n = blockIdx.x * 256 + tid;
        const float* pp = Pm + n * 3;
        float p0 = pp[0], p1 = pp[1], p2 = pp[2];
        unsigned u0 = f2bf(p0), u1 = f2bf(p1), u2 = f2bf(p2);
        unsigned v0 = f2bf(p0 - bf2f((unsigned short)u0));
        unsigned v1 = f2bf(p1 - bf2f((unsigned short)u1));
        unsigned v2 = f2bf(p2 - bf2f((unsigned short)u2));
        uint4 lo, hi;
        lo.x = u0 | (u1 << 16); lo.y = u2 | (v0 << 16);
        lo.z = v1 | (v2 << 16); lo.w = u0 | (u1 << 16);
        hi.x = u2; hi.y = 0u; hi.z = 0u; hi.w = 0u;
        *(uint4*)&eb[n * 16 + 0] = lo;
        *(uint4*)&eb[n * 16 + 8] = hi;
    }

    f32x4 acc[4][4];
    #pragma unroll
    for (int i = 0; i < 4; ++i)
        #pragma unroll
        for (int j = 0; j < 4; ++j) acc[i][j] = (f32x4){0.f, 0.f, 0.f, 0.f};

    const int srow = tid >> 1, soff = (tid & 1) * 16;   // 128 rows x 32 cols staging

    for (int k0 = 0; k0 < 256; k0 += 32) {
        __syncthreads();
        {
            const float* sa = &x [(size_t)(m0 + srow) * 256 + k0 + soff];
            const float* sw = &qw[(size_t)(o0 + srow) * 256 + k0 + soff];
            float4 a0 = *(const float4*)(sa + 0),  a1 = *(const float4*)(sa + 4);
            float4 a2 = *(const float4*)(sa + 8),  a3 = *(const float4*)(sa + 12);
            float4 b0 = *(const float4*)(sw + 0),  b1 = *(const float4*)(sw + 4);
            float4 b2 = *(const float4*)(sw + 8),  b3 = *(const float4*)(sw + 12);
            uint4 ua, ub;
            ua.x = pack2(a0.x, a0.y); ua.y = pack2(a0.z, a0.w);
            ua.z = pack2(a1.x, a1.y); ua.w = pack2(a1.z, a1.w);
            *(uint4*)&As[srow * 40 + soff + 0] = ua;
            ua.x = pack2(a2.x, a2.y); ua.y = pack2(a2.z, a2.w);
            ua.z = pack2(a3.x, a3.y); ua.w = pack2(a3.z, a3.w);
            *(uint4*)&As[srow * 40 + soff + 8] = ua;
            ub.x = pack2(b0.x, b0.y); ub.y = pack2(b0.z, b0.w);
            ub.z = pack2(b1.x, b1.y); ub.w = pack2(b1.z, b1.w);
            *(uint4*)&Bs[srow * 40 + soff + 0] = ub;
            ub.x = pack2(b2.x, b2.y); ub.y = pack2(b2.z, b2.w);
            ub.z = pack2(b3.x, b3.y); ub.w = pack2(b3.z, b3.w);
            *(uint4*)&Bs[srow * 40 + soff + 8] = ub;
        }
        __syncthreads();
        bf16x8 a[4], b[4];
        #pragma unroll
        for (int mt = 0; mt < 4; ++mt) a[mt] = ld_frag(&As[(wy * 64 + mt * 16 + l16) * 40 + quad * 8]);
        #pragma unroll
        for (int nt = 0; nt < 4; ++nt) b[nt] = ld_frag(&Bs[(wx * 64 + nt * 16 + l16) * 40 + quad * 8]);
        #pragma unroll
        for (int mt = 0; mt < 4; ++mt)
            #pragma unroll
            for (int nt = 0; nt < 4; ++nt)
                acc[mt][nt] = __builtin_amdgcn_mfma_f32_16x16x32_bf16(a[mt], b[nt], acc[mt][nt], 0, 0, 0);
    }

    const int sec = o0 + wx * 64;            // this wave's 64 output cols
    const int three = sec >> 8;
    const int h = (sec >> 6) & 3;
    const int b = m0 >> 11;
    float bv[4];
    #pragma unroll
    for (int nt = 0; nt < 4; ++nt) bv[nt] = bias[sec + nt * 16 + l16];

    if (three == 2) {
        // V: n = m0 + wy*64 + mt*16 + quad*4 + r; p = 16*quad + 4*r + mt (mt fast)
        const int n64 = (m0 + wy * 64) & 2047;
        const size_t bh64 = ((size_t)b * H_ + h) * 64;
        #pragma unroll
        for (int nt = 0; nt < 4; ++nt) {
            int d = nt * 16 + l16;
            #pragma unroll
            for (int r = 0; r < 4; ++r) {
                ushort4 v;
                v.x = f2bf(acc[0][nt][r] + bv[nt]);
                v.y = f2bf(acc[1][nt][r] + bv[nt]);
                v.z = f2bf(acc[2][nt][r] + bv[nt]);
                v.w = f2bf(acc[3][nt][r] + bv[nt]);
                *(ushort4*)&vt[(bh64 + d) * N_ + n64 + 16 * quad + 4 * r] = v;
            }
        }
    } else {
        unsigned short* dst = (three == 0) ? qb : kb;
        float sc = (three == 0) ? (0.125f * LOG2E) : 1.0f;
        #pragma unroll
        for (int mt = 0; mt < 4; ++mt)
            #pragma unroll
            for (int r = 0; r < 4; ++r) {
                int n = (m0 + wy * 64 + mt * 16 + quad * 4 + r) & 2047;
                size_t rowbase = (((size_t)b * H_ + h) * N_ + n) * D_;
                #pragma unroll
                for (int nt = 0; nt < 4; ++nt)
                    dst[rowbase + nt * 16 + l16] = f2bf((acc[mt][nt][r] + bv[nt]) * sc);
            }
    }
}

// ---------------- Flash attention: split-K x2, bias in MFMA -------------------
// DMA pipeline: global_load_lds into double-buffered Ks/Vs (linear dest,
// pre-swizzled global source); one barrier/iter. Ext from precomputed eb
// table straight into registers. DPP-based (VALU-latency) max reduce.
#define LDK 64   // Ks/Vs/Ps row stride in shorts (128 B, 8 slots of 16 B)

__global__ __launch_bounds__(256) void attn_kernel(
    const unsigned short* __restrict__ qb, const unsigned short* __restrict__ kb,
    const unsigned short* __restrict__ vt, const unsigned short* __restrict__ eb,
    const float* __restrict__ Rm, const float* __restrict__ Pm,
    const float* __restrict__ ps_ptr,
    unsigned short* __restrict__ Opart, float* __restrict__ ml)
{
    __shared__ __align__(16) unsigned short Ks[2][64 * LDK]; // 16 KB
    __shared__ __align__(16) unsigned short Vs[2][64 * LDK]; // 16 KB
    __shared__ __align__(16) unsigned short Ps[64 * LDK];    // 8 KB

    const int bh = blockIdx.y;
    const int b = bh >> 2;
    const int i0 = blockIdx.x * 64;
    const int split = blockIdx.z;
    const int tid = threadIdx.x;
    const int wave = tid >> 6, lane = tid & 63;
    const int quad = lane >> 4, l16 = lane & 15;
    const int x7 = l16 & 7;
    const float ps = ps_ptr[0];

    const size_t base = (size_t)bh * N_ * D_;
    const unsigned short* qg = qb + base;
    const unsigned short* kg = kb + base;
    const unsigned short* vg = vt + base;   // rows of length N_

    const int jbeg = split * (N_ / 2);
    const int NT = (N_ / 2) / 64;

    // ---- DMA source pointers (pre-swizzled), advanced per tile ----
    const int rl = lane >> 3, sl = lane & 7;          // 8 rows x 8 slots per issue
    const int swz = (sl ^ rl) * 8;
    const unsigned short* kq = kg + (size_t)(jbeg + wave * 16 + rl) * D_ + swz;
    const unsigned short* vq = vg + (size_t)(wave * 16 + rl) * N_ + jbeg + swz;
    const unsigned short* ep = eb + (size_t)(jbeg + l16) * 16 + (quad & 1) * 8;

    auto ISSUE = [&](int nb) {
        unsigned short* kd = &Ks[nb][(wave * 16) * LDK];
        unsigned short* vd = &Vs[nb][(wave * 16) * LDK];
        gload_lds16(kq,           kd);
        gload_lds16(kq + 8 * D_,  kd + 8 * LDK);
        gload_lds16(vq,           vd);
        gload_lds16(vq + 8 * N_,  vd + 8 * LDK);
    };

    // prologue: tile 0 DMA + ext frags
    ISSUE(0);
    kq += 64 * D_; vq += 64;
    bf16x8 ereg[4];
    #pragma unroll
    for (int t = 0; t < 4; ++t) ereg[t] = ld_frag(ep + t * 256);
    ep += 64 * 16;

    // Q A-fragments (pre-scaled by 0.125*log2e)
    const int qrow = i0 + wave * 16 + l16;
    bf16x8 aq[3];
    #pragma unroll
    for (int ks = 0; ks < 2; ++ks)
        aq[ks] = ld_frag(&qg[(size_t)qrow * D_ + ks * 32 + quad * 8]);

    // A-side bias ext: a = ps*log2e*(R_b @ P_qrow), hi/lo split
    {
        float p0 = Pm[qrow * 3 + 0], p1 = Pm[qrow * 3 + 1], p2 = Pm[qrow * 3 + 2];
        float sc = ps * LOG2E;
        unsigned short ah[3], al[3];
        #pragma unroll
        for (int c = 0; c < 3; ++c) {
            float a = (Rm[b * 9 + c * 3 + 0] * p0 + Rm[b * 9 + c * 3 + 1] * p1
                     + Rm[b * 9 + c * 3 + 2] * p2) * sc;
            ah[c] = f2bf(a);
            al[c] = f2bf(a - bf2f(ah[c]));
        }
        bf16x8 e = (bf16x8){0,0,0,0,0,0,0,0};
        if (quad == 0) {
            e[0] = (short)ah[0]; e[1] = (short)ah[1]; e[2] = (short)ah[2];
            e[3] = (short)ah[0]; e[4] = (short)ah[1]; e[5] = (short)ah[2];
            e[6] = (short)al[0]; e[7] = (short)al[1];
        } else if (quad == 1) {
            e[0] = (short)al[2];
        }
        aq[2] = e;
    }

    const bf16x8 ones = (bf16x8){0x3F80,0x3F80,0x3F80,0x3F80,0x3F80,0x3F80,0x3F80,0x3F80};

    float m_run = -1e30f;
    f32x4 o_acc[4], lacc;
    #pragma unroll
    for (int t = 0; t < 4; ++t) o_acc[t] = (f32x4){0.f, 0.f, 0.f, 0.f};
    lacc = (f32x4){0.f, 0.f, 0.f, 0.f};

    for (int jt = 0; jt < NT; ++jt) {
        const int cur = jt & 1;
        // arrival of tile jt's DMA + everyone done reading buffer cur^1
        asm volatile("s_waitcnt vmcnt(0)" ::: "memory");
        __syncthreads();
        if (jt + 1 < NT) {          // issue next tile into freed buffer
            ISSUE(cur ^ 1);
            kq += 64 * D_; vq += 64;
        }

        // S (log2-domain logits incl. bias): (2 K-steps from LDS + ext) x 4 tiles
        f32x4 s[4];
        __builtin_amdgcn_s_setprio(1);
        #pragma unroll
        for (int t = 0; t < 4; ++t) {
            const int rb = (l16 + 16 * t) * LDK;
            f32x4 c = {0.f, 0.f, 0.f, 0.f};
            #pragma unroll
            for (int ks = 0; ks < 2; ++ks) {
                bf16x8 bk = ld_frag(&Ks[cur][rb + (((ks * 4 + quad) ^ x7) * 8)]);
                c = __builtin_amdgcn_mfma_f32_16x16x32_bf16(aq[ks], bk, c, 0, 0, 0);
            }
            c = __builtin_amdgcn_mfma_f32_16x16x32_bf16(aq[2], ereg[t], c, 0, 0, 0);
            s[t] = c;
        }
        __builtin_amdgcn_s_setprio(0);

        // prefetch next tile's ext frags (consumed next iteration)
        if (jt + 1 < NT) {
            #pragma unroll
            for (int t = 0; t < 4; ++t) ereg[t] = ld_frag(ep + t * 256);
            ep += 64 * 16;
        }

        // per-quad (4-row-group) max: local tree + 4 DPP steps (16-lane scope)
        float mt[4];
        #pragma unroll
        for (int t = 0; t < 4; ++t)
            mt[t] = fmaxf(fmaxf(s[t][0], s[t][1]), fmaxf(s[t][2], s[t][3]));
        float mx = fmaxf(fmaxf(mt[0], mt[1]), fmaxf(mt[2], mt[3]));
        mx = fmax_dpp<0xB1>(mx);    // quad_perm [1,0,3,2]  (xor 1)
        mx = fmax_dpp<0x4E>(mx);    // quad_perm [2,3,0,1]  (xor 2)
        mx = fmax_dpp<0x124>(mx);   // row_ror:4
        mx = fmax_dpp<0x128>(mx);   // row_ror:8

        // defer-max: rescale only when some quad's max grew by > 8
        if (__any(mx > m_run + 8.0f)) {
            float mnew = fmaxf(m_run, mx);
            float alpha = exp2f(m_run - mnew);
            #pragma unroll
            for (int t = 0; t < 4; ++t)
                #pragma unroll
                for (int r = 0; r < 4; ++r)
                    o_acc[t][r] *= alpha;
            #pragma unroll
            for (int r = 0; r < 4; ++r) lacc[r] *= alpha;
            m_run = mnew;
        }

        // p = exp2(lg - m_run); pack into Ps at perm position 4*l16 + t
        #pragma unroll
        for (int r = 0; r < 4; ++r) {
            float p0 = exp2f(s[0][r] - m_run), p1 = exp2f(s[1][r] - m_run);
            float p2 = exp2f(s[2][r] - m_run), p3 = exp2f(s[3][r] - m_run);
            uint2 w;
            w.x = pack2(p0, p1);
            w.y = pack2(p2, p3);
            const int prow = quad * 4 + r;
            *(uint2*)&Ps[(wave * 16 + prow) * LDK
                         + (((l16 >> 1) ^ (prow & 7)) * 8) + (l16 & 1) * 4] = w;
        }

        // O += P V; l += P . 1 (ones-MFMA)
        __builtin_amdgcn_s_setprio(1);
        #pragma unroll
        for (int ks = 0; ks < 2; ++ks) {
            bf16x8 ap = ld_frag(&Ps[(wave * 16 + l16) * LDK
                                    + (((ks * 4 + quad) ^ x7) * 8)]);
            #pragma unroll
            for (int t = 0; t < 4; ++t) {
                bf16x8 bv = ld_frag(&Vs[cur][(l16 + 16 * t) * LDK
                                             + (((ks * 4 + quad) ^ x7) * 8)]);
                o_acc[t] = __builtin_amdgcn_mfma_f32_16x16x32_bf16(ap, bv, o_acc[t], 0, 0, 0);
            }
            lacc = __builtin_amdgcn_mfma_f32_16x16x32_bf16(ap, ones, lacc, 0, 0, 0);
        }
        __builtin_amdgcn_s_setprio(0);
    }

    // store unnormalized partial O (bf16) + (m,l) per row
    const size_t pbase = (size_t)(split * 16 + bh) * N_;
    #pragma unroll
    for (int r = 0; r < 4; ++r) {
        int row = i0 + wave * 16 + quad * 4 + r;
        #pragma unroll
        for (int t = 0; t < 4; ++t)
            Opart[(pbase + row) * D_ + l16 + 16 * t] = f2bf(o_acc[t][r]);
        if (l16 == 0) {
            float2* mlp = (float2*)ml;
            mlp[pbase + row] = make_float2(m_run, lacc[r]);
        }
    }
}

// ---------------- Output projection: fused 2-way merge, f32 weights ----------
// 64x64 tile, 4 waves on M; proj_w converted to bf16 during staging.
__global__ __launch_bounds__(256) void proj_gemm(
    const unsigned short* __restrict__ Opart, const float* __restrict__ ml,
    const float* __restrict__ pw, const float* __restrict__ bias,
    float* __restrict__ out)
{
    __shared__ __align__(16) unsigned short As[64 * 40];
    __shared__ __align__(16) unsigned short Bs[64 * 40];
    const int m0 = blockIdx.x * 64, o0 = blockIdx.y * 64;
    const int tid = threadIdx.x;
    const int wave = tid >> 6, lane = tid & 63, quad = lane >> 4, l16 = lane & 15;
    const float2* mlp = (const float2*)ml;

    const int srow = tid >> 2, scb = (tid & 3) * 8;
    const int sm = m0 + srow, sb = sm >> 11, sn = sm & 2047;

    // hoist 2-way merge weights per h
    float w1h[4], w2h[4];
    #pragma unroll
    for (int h = 0; h < 4; ++h) {
        size_t r1 = (size_t)(sb * 4 + h) * N_ + sn;
        float2 ml1 = mlp[r1], ml2 = mlp[r1 + 16 * N_];
        float mm = fmaxf(ml1.x, ml2.x);
        float w1 = exp2f(ml1.x - mm), w2 = exp2f(ml2.x - mm);
        float inv = 1.f / (ml1.y * w1 + ml2.y * w2);
        w1h[h] = w1 * inv; w2h[h] = w2 * inv;
    }

    f32x4 acc[4];
    #pragma unroll
    for (int j = 0; j < 4; ++j) acc[j] = (f32x4){0.f, 0.f, 0.f, 0.f};

    for (int k0 = 0; k0 < 256; k0 += 32) {
        const int h = k0 >> 6;
        const int d0 = (k0 & 63) + scb;
        __syncthreads();
        {   // A: 2-way merge -> bf16; B: f32 -> bf16 convert
            size_t r1 = (size_t)(sb * 4 + h) * N_ + sn;
            union { uint4 u; unsigned short s[8]; } a1, a2;
            a1.u = *(const uint4*)&Opart[r1 * D_ + d0];
            a2.u = *(const uint4*)&Opart[(r1 + 16 * N_) * D_ + d0];
            float w1 = w1h[h], w2 = w2h[h];
            uint4 mv;
            unsigned* mp = (unsigned*)&mv;
            #pragma unroll
            for (int j = 0; j < 4; ++j)
                mp[j] = pack2(bf2f(a1.s[2*j]) * w1 + bf2f(a2.s[2*j]) * w2,
                              bf2f(a1.s[2*j+1]) * w1 + bf2f(a2.s[2*j+1]) * w2);
            *(uint4*)&As[srow * 40 + scb] = mv;
            const float* sw = &pw[(size_t)(o0 + srow) * 256 + k0 + scb];
            float4 b0 = *(const float4*)(sw + 0), b1 = *(const float4*)(sw + 4);
            uint4 ub;
            ub.x = pack2(b0.x, b0.y); ub.y = pack2(b0.z, b0.w);
            ub.z = pack2(b1.x, b1.y); ub.w = pack2(b1.z, b1.w);
            *(uint4*)&Bs[srow * 40 + scb] = ub;
        }
        __syncthreads();
        bf16x8 a = ld_frag(&As[(wave * 16 + l16) * 40 + quad * 8]);
        #pragma unroll
        for (int nt = 0; nt < 4; ++nt) {
            bf16x8 b = ld_frag(&Bs[(nt * 16 + l16) * 40 + quad * 8]);
            acc[nt] = __builtin_amdgcn_mfma_f32_16x16x32_bf16(a, b, acc[nt], 0, 0, 0);
        }
    }

    float bv[4];
    #pragma unroll
    for (int nt = 0; nt < 4; ++nt) bv[nt] = bias[o0 + nt * 16 + l16];
    #pragma unroll
    for (int r = 0; r < 4; ++r) {
        int m = m0 + wave * 16 + quad * 4 + r;
        #pragma unroll
        for (int nt = 0; nt < 4; ++nt)
            out[(size_t)m * 256 + o0 + nt * 16 + l16] = acc[nt][r] + bv[nt];
    }
}

extern "C" void kernel_launch(void* const* d_in, const int* in_sizes, int n_in,
                              void* d_out, int out_size, void* d_ws, size_t ws_size,
                              hipStream_t stream) {
    const float* x       = (const float*)d_in[0];
    const float* Rm      = (const float*)d_in[1];
    const float* Pm      = (const float*)d_in[2];
    const float* qkv_w   = (const float*)d_in[3];
    const float* qkv_b   = (const float*)d_in[4];
    const float* proj_w  = (const float*)d_in[5];
    const float* proj_b  = (const float*)d_in[6];
    const float* pos_scl = (const float*)d_in[7];
    float* out = (float*)d_out;

    const size_t NE = (size_t)B_ * H_ * N_ * D_;   // 2,097,152
    unsigned short* qb    = (unsigned short*)d_ws; // 4 MB each
    unsigned short* kb    = qb   + NE;
    unsigned short* vtb   = kb   + NE;
    unsigned short* opart = vtb  + NE;             // 2*NE = 8 MB
    float*          mlb   = (float*)(opart + 2 * NE);  // 2*16*2048 float2 = 512 KB
    unsigned short* eb    = (unsigned short*)(mlb + 2 * 16 * N_ * 2); // 64 KB ext table

    qkv_gemm<<<dim3(64, 6), 256, 0, stream>>>(x, qkv_w, qkv_b, Pm, qb, kb, vtb, eb);
    attn_kernel<<<dim3(32, 16, 2), 256, 0, stream>>>(qb, kb, vtb, eb, Rm, Pm, pos_scl, opart, mlb);
    proj_gemm<<<dim3(128, 4), 256, 0, stream>>>(opart, mlb, proj_w, proj_b, out);
}

// Round 4
// 143.829 us; speedup vs baseline: 1.0776x; 1.0050x over previous
//
#include <hip/hip_runtime.h>
#include <hip/hip_bf16.h>

#define B_ 4
#define N_ 2048
#define C_ 256
#define H_ 4
#define D_ 64

typedef __attribute__((ext_vector_type(8))) short bf16x8;
typedef __attribute__((ext_vector_type(4))) float f32x4;

#define LOG2E 1.4426950408889634f

// f32 -> bf16 round-to-nearest-even (scalar)
static __device__ inline unsigned short f2bf(float f) {
    unsigned u = __builtin_bit_cast(unsigned, f);
    unsigned r = (u + 0x7fffu + ((u >> 16) & 1u)) >> 16;
    return (unsigned short)r;
}
static __device__ inline float bf2f(unsigned short h) {
    unsigned u = ((unsigned)h) << 16;
    return __builtin_bit_cast(float, u);
}
// packed pair f32 -> bf16x2
static __device__ inline unsigned pack2(float a, float b) {
    __hip_bfloat162 h = __float22bfloat162_rn(make_float2(a, b));
    unsigned u;
    __builtin_memcpy(&u, &h, 4);
    return u;
}
static __device__ inline bf16x8 ld_frag(const unsigned short* p) {
    return __builtin_bit_cast(bf16x8, *(const uint4*)p);
}
// async global->LDS DMA, 16B per lane, dest = ldsbase + lane*16
static __device__ inline void gload_lds16(const unsigned short* g, unsigned short* l) {
    __builtin_amdgcn_global_load_lds(
        (const __attribute__((address_space(1))) unsigned int*)(g),
        (__attribute__((address_space(3))) unsigned int*)(l),
        16, 0, 0);
}
// fmax with a DPP-permuted copy (VALU-latency cross-lane, 16-lane row scope)
template<int CTRL>
static __device__ inline float fmax_dpp(float x) {
    int yi = __builtin_amdgcn_update_dpp(0, __builtin_bit_cast(int, x),
                                         CTRL, 0xf, 0xf, true);
    return fmaxf(x, __builtin_bit_cast(float, yi));
}

// ---------------- cvt prepass: x / qkv_w / proj_w -> bf16; Pm -> ext table ----
// ext row (16 shorts) per key n: [ph0,ph1,ph2,pl0,pl1,pl2,ph0,ph1 | ph2,0,..,0]
__global__ __launch_bounds__(256) void cvt_kernel(
    const float* __restrict__ x, const float* __restrict__ qkv_w,
    const float* __restrict__ proj_w, const float* __restrict__ Pm,
    unsigned short* __restrict__ xb, unsigned short* __restrict__ wqb,
    unsigned short* __restrict__ wpb, unsigned short* __restrict__ eb)
{
    const int bid = blockIdx.x, tid = threadIdx.x;
    if (bid >= 1152) {
        const int n = (bid - 1152) * 256 + tid;
        const float* pp = Pm + n * 3;
        float p0 = pp[0], p1 = pp[1], p2 = pp[2];
        unsigned u0 = f2bf(p0), u1 = f2bf(p1), u2 = f2bf(p2);
        unsigned v0 = f2bf(p0 - bf2f((unsigned short)u0));
        unsigned v1 = f2bf(p1 - bf2f((unsigned short)u1));
        unsigned v2 = f2bf(p2 - bf2f((unsigned short)u2));
        uint4 lo, hi;
        lo.x = u0 | (u1 << 16); lo.y = u2 | (v0 << 16);
        lo.z = v1 | (v2 << 16); lo.w = u0 | (u1 << 16);
        hi.x = u2; hi.y = 0u; hi.z = 0u; hi.w = 0u;
        *(uint4*)&eb[n * 16 + 0] = lo;
        *(uint4*)&eb[n * 16 + 8] = hi;
        return;
    }
    const float* s; unsigned short* d; int i;
    if (bid < 1024)      { s = x;      d = xb;  i = (bid * 256 + tid) * 8; }
    else if (bid < 1120) { s = qkv_w;  d = wqb; i = ((bid - 1024) * 256 + tid) * 8; }
    else                 { s = proj_w; d = wpb; i = ((bid - 1120) * 256 + tid) * 8; }
    float4 a = *(const float4*)(s + i);
    float4 b = *(const float4*)(s + i + 4);
    uint4 u;
    u.x = pack2(a.x, a.y); u.y = pack2(a.z, a.w);
    u.z = pack2(b.x, b.y); u.w = pack2(b.z, b.w);
    *(uint4*)(d + i) = u;
}

// ---------------- QKV GEMM: bf16, 128x128 tile, 4 waves 2x2, BK=32 ----------
// Q pre-scaled by 0.125*log2e. V written transposed+permuted:
// vt[bh][d][n_perm], perm within 64-block: p = 4*(n&15)+((n>>4)&3).
__global__ __launch_bounds__(256) void qkv_gemm(
    const unsigned short* __restrict__ xb, const unsigned short* __restrict__ wb,
    const float* __restrict__ bias, unsigned short* __restrict__ qb,
    unsigned short* __restrict__ kb, unsigned short* __restrict__ vt)
{
    __shared__ __align__(16) unsigned short As[128 * 40];
    __shared__ __align__(16) unsigned short Bs[128 * 40];
    const int m0 = blockIdx.x * 128, o0 = blockIdx.y * 128;
    const int tid = threadIdx.x;
    const int wave = tid >> 6, lane = tid & 63, quad = lane >> 4, l16 = lane & 15;
    const int wy = wave >> 1, wx = wave & 1;

    f32x4 acc[4][4];
    #pragma unroll
    for (int i = 0; i < 4; ++i)
        #pragma unroll
        for (int j = 0; j < 4; ++j) acc[i][j] = (f32x4){0.f, 0.f, 0.f, 0.f};

    const int srow = tid >> 1, soff = (tid & 1) * 16;   // 128 rows x 32 cols staging

    for (int k0 = 0; k0 < 256; k0 += 32) {
        __syncthreads();
        {
            const unsigned short* sa = &xb[(size_t)(m0 + srow) * 256 + k0 + soff];
            const unsigned short* sb = &wb[(size_t)(o0 + srow) * 256 + k0 + soff];
            *(uint4*)&As[srow * 40 + soff + 0] = *(const uint4*)(sa + 0);
            *(uint4*)&As[srow * 40 + soff + 8] = *(const uint4*)(sa + 8);
            *(uint4*)&Bs[srow * 40 + soff + 0] = *(const uint4*)(sb + 0);
            *(uint4*)&Bs[srow * 40 + soff + 8] = *(const uint4*)(sb + 8);
        }
        __syncthreads();
        bf16x8 a[4], b[4];
        #pragma unroll
        for (int mt = 0; mt < 4; ++mt) a[mt] = ld_frag(&As[(wy * 64 + mt * 16 + l16) * 40 + quad * 8]);
        #pragma unroll
        for (int nt = 0; nt < 4; ++nt) b[nt] = ld_frag(&Bs[(wx * 64 + nt * 16 + l16) * 40 + quad * 8]);
        #pragma unroll
        for (int mt = 0; mt < 4; ++mt)
            #pragma unroll
            for (int nt = 0; nt < 4; ++nt)
                acc[mt][nt] = __builtin_amdgcn_mfma_f32_16x16x32_bf16(a[mt], b[nt], acc[mt][nt], 0, 0, 0);
    }

    const int sec = o0 + wx * 64;            // this wave's 64 output cols
    const int three = sec >> 8;
    const int h = (sec >> 6) & 3;
    const int b = m0 >> 11;
    float bv[4];
    #pragma unroll
    for (int nt = 0; nt < 4; ++nt) bv[nt] = bias[sec + nt * 16 + l16];

    if (three == 2) {
        // V: n = m0 + wy*64 + mt*16 + quad*4 + r; p = 16*quad + 4*r + mt (mt fast)
        const int n64 = (m0 + wy * 64) & 2047;
        const size_t bh64 = ((size_t)b * H_ + h) * 64;
        #pragma unroll
        for (int nt = 0; nt < 4; ++nt) {
            int d = nt * 16 + l16;
            #pragma unroll
            for (int r = 0; r < 4; ++r) {
                ushort4 v;
                v.x = f2bf(acc[0][nt][r] + bv[nt]);
                v.y = f2bf(acc[1][nt][r] + bv[nt]);
                v.z = f2bf(acc[2][nt][r] + bv[nt]);
                v.w = f2bf(acc[3][nt][r] + bv[nt]);
                *(ushort4*)&vt[(bh64 + d) * N_ + n64 + 16 * quad + 4 * r] = v;
            }
        }
    } else {
        unsigned short* dst = (three == 0) ? qb : kb;
        float sc = (three == 0) ? (0.125f * LOG2E) : 1.0f;
        #pragma unroll
        for (int mt = 0; mt < 4; ++mt)
            #pragma unroll
            for (int r = 0; r < 4; ++r) {
                int n = (m0 + wy * 64 + mt * 16 + quad * 4 + r) & 2047;
                size_t rowbase = (((size_t)b * H_ + h) * N_ + n) * D_;
                #pragma unroll
                for (int nt = 0; nt < 4; ++nt)
                    dst[rowbase + nt * 16 + l16] = f2bf((acc[mt][nt][r] + bv[nt]) * sc);
            }
    }
}

// ---------------- Flash attention: split-K x4, counted-vmcnt pipeline --------
// Ks double-buffered, Vs single-buffered (issued at top, landed by PV via
// vmcnt(2)); raw s_barriers, no full drains in the loop body (T4).
// 32 KB LDS -> 5 blocks/CU capacity; grid 2048 blocks (8 assigned/CU).
#define LDK 64   // Ks/Vs/Ps row stride in shorts (128 B, 8 slots of 16 B)

__global__ __launch_bounds__(256) void attn_kernel(
    const unsigned short* __restrict__ qb, const unsigned short* __restrict__ kb,
    const unsigned short* __restrict__ vt, const unsigned short* __restrict__ eb,
    const float* __restrict__ Rm, const float* __restrict__ Pm,
    const float* __restrict__ ps_ptr,
    unsigned short* __restrict__ Opart, float* __restrict__ ml)
{
    __shared__ __align__(16) unsigned short Ks[2][64 * LDK]; // 16 KB
    __shared__ __align__(16) unsigned short Vs[64 * LDK];    // 8 KB
    __shared__ __align__(16) unsigned short Ps[64 * LDK];    // 8 KB

    const int bh = blockIdx.y;
    const int b = bh >> 2;
    const int i0 = blockIdx.x * 64;
    const int split = blockIdx.z;
    const int tid = threadIdx.x;
    const int wave = tid >> 6, lane = tid & 63;
    const int quad = lane >> 4, l16 = lane & 15;
    const int x7 = l16 & 7;
    const float ps = ps_ptr[0];

    const size_t base = (size_t)bh * N_ * D_;
    const unsigned short* qg = qb + base;
    const unsigned short* kg = kb + base;
    const unsigned short* vg = vt + base;   // rows of length N_

    const int jbeg = split * (N_ / 4);
    const int NT = (N_ / 4) / 64;           // 8

    // ---- DMA source pointers (pre-swizzled), advanced per tile ----
    const int rl = lane >> 3, sl = lane & 7;          // 8 rows x 8 slots per issue
    const int swz = (sl ^ rl) * 8;
    const unsigned short* kq = kg + (size_t)(jbeg + wave * 16 + rl) * D_ + swz;
    const unsigned short* vq = vg + (size_t)(wave * 16 + rl) * N_ + jbeg + swz;
    const unsigned short* ep = eb + (size_t)(jbeg + l16) * 16 + (quad & 1) * 8;

    // prologue: K(0) DMA + ext(0) regs
    {
        unsigned short* kd = &Ks[0][(wave * 16) * LDK];
        gload_lds16(kq,          kd);
        gload_lds16(kq + 8 * D_, kd + 8 * LDK);
        kq += 64 * D_;
    }
    bf16x8 ereg[4];
    #pragma unroll
    for (int t = 0; t < 4; ++t) ereg[t] = ld_frag(ep + t * 256);
    ep += 64 * 16;

    // Q A-fragments (pre-scaled by 0.125*log2e)
    const int qrow = i0 + wave * 16 + l16;
    bf16x8 aq[3];
    #pragma unroll
    for (int ks = 0; ks < 2; ++ks)
        aq[ks] = ld_frag(&qg[(size_t)qrow * D_ + ks * 32 + quad * 8]);

    // A-side bias ext: a = ps*log2e*(R_b @ P_qrow), hi/lo split
    {
        float p0 = Pm[qrow * 3 + 0], p1 = Pm[qrow * 3 + 1], p2 = Pm[qrow * 3 + 2];
        float sc = ps * LOG2E;
        unsigned short ah[3], al[3];
        #pragma unroll
        for (int c = 0; c < 3; ++c) {
            float a = (Rm[b * 9 + c * 3 + 0] * p0 + Rm[b * 9 + c * 3 + 1] * p1
                     + Rm[b * 9 + c * 3 + 2] * p2) * sc;
            ah[c] = f2bf(a);
            al[c] = f2bf(a - bf2f(ah[c]));
        }
        bf16x8 e = (bf16x8){0,0,0,0,0,0,0,0};
        if (quad == 0) {
            e[0] = (short)ah[0]; e[1] = (short)ah[1]; e[2] = (short)ah[2];
            e[3] = (short)ah[0]; e[4] = (short)ah[1]; e[5] = (short)ah[2];
            e[6] = (short)al[0]; e[7] = (short)al[1];
        } else if (quad == 1) {
            e[0] = (short)al[2];
        }
        aq[2] = e;
    }

    const bf16x8 ones = (bf16x8){0x3F80,0x3F80,0x3F80,0x3F80,0x3F80,0x3F80,0x3F80,0x3F80};

    float m_run = -1e30f;
    f32x4 o_acc[4], lacc;
    #pragma unroll
    for (int t = 0; t < 4; ++t) o_acc[t] = (f32x4){0.f, 0.f, 0.f, 0.f};
    lacc = (f32x4){0.f, 0.f, 0.f, 0.f};

    for (int jt = 0; jt < NT; ++jt) {
        const int cur = jt & 1;
        const bool more = (jt + 1 < NT);

        // K(jt)+ext(jt) landed (issued a full iteration ago -> near-free wait)
        asm volatile("s_waitcnt vmcnt(0)" ::: "memory");
        __builtin_amdgcn_s_barrier();
        __builtin_amdgcn_sched_barrier(0);

        // top cluster: ext(jt+1) reg-prefetch, V(jt) DMA, K(jt+1) DMA
        bf16x8 enext[4];
        if (more) {
            #pragma unroll
            for (int t = 0; t < 4; ++t) enext[t] = ld_frag(ep + t * 256);
            ep += 64 * 16;
        }
        {
            unsigned short* vd = &Vs[(wave * 16) * LDK];
            gload_lds16(vq,          vd);
            gload_lds16(vq + 8 * N_, vd + 8 * LDK);
            vq += 64;
        }
        if (more) {
            unsigned short* kd = &Ks[cur ^ 1][(wave * 16) * LDK];
            gload_lds16(kq,          kd);
            gload_lds16(kq + 8 * D_, kd + 8 * LDK);
            kq += 64 * D_;
        }
        __builtin_amdgcn_sched_barrier(0);

        // S (log2-domain logits incl. bias): (2 K-steps from LDS + ext) x 4 tiles
        f32x4 s[4];
        __builtin_amdgcn_s_setprio(1);
        #pragma unroll
        for (int t = 0; t < 4; ++t) {
            const int rb = (l16 + 16 * t) * LDK;
            f32x4 c = {0.f, 0.f, 0.f, 0.f};
            #pragma unroll
            for (int ks = 0; ks < 2; ++ks) {
                bf16x8 bk = ld_frag(&Ks[cur][rb + (((ks * 4 + quad) ^ x7) * 8)]);
                c = __builtin_amdgcn_mfma_f32_16x16x32_bf16(aq[ks], bk, c, 0, 0, 0);
            }
            c = __builtin_amdgcn_mfma_f32_16x16x32_bf16(aq[2], ereg[t], c, 0, 0, 0);
            s[t] = c;
        }
        __builtin_amdgcn_s_setprio(0);
        if (more) {
            #pragma unroll
            for (int t = 0; t < 4; ++t) ereg[t] = enext[t];
        }

        // per-quad (4-row-group) max: local tree + 4 DPP steps (16-lane scope)
        float mt[4];
        #pragma unroll
        for (int t = 0; t < 4; ++t)
            mt[t] = fmaxf(fmaxf(s[t][0], s[t][1]), fmaxf(s[t][2], s[t][3]));
        float mx = fmaxf(fmaxf(mt[0], mt[1]), fmaxf(mt[2], mt[3]));
        mx = fmax_dpp<0xB1>(mx);    // quad_perm [1,0,3,2]  (xor 1)
        mx = fmax_dpp<0x4E>(mx);    // quad_perm [2,3,0,1]  (xor 2)
        mx = fmax_dpp<0x124>(mx);   // row_ror:4
        mx = fmax_dpp<0x128>(mx);   // row_ror:8

        // defer-max: rescale only when the max grew by > 8
        if (__any(mx > m_run + 8.0f)) {
            float mnew = fmaxf(m_run, mx);
            float alpha = exp2f(m_run - mnew);
            #pragma unroll
            for (int t = 0; t < 4; ++t)
                #pragma unroll
                for (int r = 0; r < 4; ++r)
                    o_acc[t][r] *= alpha;
            #pragma unroll
            for (int r = 0; r < 4; ++r) lacc[r] *= alpha;
            m_run = mnew;
        }

        // p = exp2(lg - m_run); pack into Ps at perm position 4*l16 + t
        #pragma unroll
        for (int r = 0; r < 4; ++r) {
            float p0 = exp2f(s[0][r] - m_run), p1 = exp2f(s[1][r] - m_run);
            float p2 = exp2f(s[2][r] - m_run), p3 = exp2f(s[3][r] - m_run);
            uint2 w;
            w.x = pack2(p0, p1);
            w.y = pack2(p2, p3);
            const int prow = quad * 4 + r;
            *(uint2*)&Ps[(wave * 16 + prow) * LDK
                         + (((l16 >> 1) ^ (prow & 7)) * 8) + (l16 & 1) * 4] = w;
        }

        // V(jt) landed: counted wait keeps K(jt+1) in flight across the barrier
        if (more) asm volatile("s_waitcnt vmcnt(2)" ::: "memory");
        else      asm volatile("s_waitcnt vmcnt(0)" ::: "memory");
        __builtin_amdgcn_s_barrier();
        __builtin_amdgcn_sched_barrier(0);

        // O += P V; l += P . 1 (ones-MFMA)
        __builtin_amdgcn_s_setprio(1);
        #pragma unroll
        for (int ks = 0; ks < 2; ++ks) {
            bf16x8 ap = ld_frag(&Ps[(wave * 16 + l16) * LDK
                                    + (((ks * 4 + quad) ^ x7) * 8)]);
            #pragma unroll
            for (int t = 0; t < 4; ++t) {
                bf16x8 bv = ld_frag(&Vs[(l16 + 16 * t) * LDK
                                        + (((ks * 4 + quad) ^ x7) * 8)]);
                o_acc[t] = __builtin_amdgcn_mfma_f32_16x16x32_bf16(ap, bv, o_acc[t], 0, 0, 0);
            }
            lacc = __builtin_amdgcn_mfma_f32_16x16x32_bf16(ap, ones, lacc, 0, 0, 0);
        }
        __builtin_amdgcn_s_setprio(0);
    }

    // store unnormalized partial O (bf16) + (m,l) per row
    const size_t pbase = (size_t)(split * 16 + bh) * N_;
    #pragma unroll
    for (int r = 0; r < 4; ++r) {
        int row = i0 + wave * 16 + quad * 4 + r;
        #pragma unroll
        for (int t = 0; t < 4; ++t)
            Opart[(pbase + row) * D_ + l16 + 16 * t] = f2bf(o_acc[t][r]);
        if (l16 == 0) {
            float2* mlp = (float2*)ml;
            mlp[pbase + row] = make_float2(m_run, lacc[r]);
        }
    }
}

// ---------------- Output projection: fused 4-way merge, hoisted weights ------
// 64x64 tile, 4 waves on M; bf16 weights from cvt prepass.
__global__ __launch_bounds__(256) void proj_gemm(
    const unsigned short* __restrict__ Opart, const float* __restrict__ ml,
    const unsigned short* __restrict__ wb, const float* __restrict__ bias,
    float* __restrict__ out)
{
    __shared__ __align__(16) unsigned short As[64 * 40];
    __shared__ __align__(16) unsigned short Bs[64 * 40];
    const int m0 = blockIdx.x * 64, o0 = blockIdx.y * 64;
    const int tid = threadIdx.x;
    const int wave = tid >> 6, lane = tid & 63, quad = lane >> 4, l16 = lane & 15;
    const float2* mlp = (const float2*)ml;

    const int srow = tid >> 2, scb = (tid & 3) * 8;
    const int sm = m0 + srow, sb = sm >> 11, sn = sm & 2047;

    // hoist 4-way merge weights per h
    float wgt[4][4];
    #pragma unroll
    for (int h = 0; h < 4; ++h) {
        size_t r1 = (size_t)(sb * 4 + h) * N_ + sn;
        float2 m0v = mlp[r1], m1v = mlp[r1 + 16 * N_];
        float2 m2v = mlp[r1 + 32 * N_], m3v = mlp[r1 + 48 * N_];
        float mm = fmaxf(fmaxf(m0v.x, m1v.x), fmaxf(m2v.x, m3v.x));
        float w0 = exp2f(m0v.x - mm), w1 = exp2f(m1v.x - mm);
        float w2 = exp2f(m2v.x - mm), w3 = exp2f(m3v.x - mm);
        float inv = 1.f / (m0v.y * w0 + m1v.y * w1 + m2v.y * w2 + m3v.y * w3);
        wgt[h][0] = w0 * inv; wgt[h][1] = w1 * inv;
        wgt[h][2] = w2 * inv; wgt[h][3] = w3 * inv;
    }

    f32x4 acc[4];
    #pragma unroll
    for (int j = 0; j < 4; ++j) acc[j] = (f32x4){0.f, 0.f, 0.f, 0.f};

    for (int k0 = 0; k0 < 256; k0 += 32) {
        const int h = k0 >> 6;
        const int d0 = (k0 & 63) + scb;
        __syncthreads();
        {   // A: 4-way merge -> bf16; B: bf16 copy
            size_t r1 = (size_t)(sb * 4 + h) * N_ + sn;
            union { uint4 u; unsigned short s[8]; } a0, a1, a2, a3;
            a0.u = *(const uint4*)&Opart[(r1 +  0 * N_) * D_ + d0];
            a1.u = *(const uint4*)&Opart[(r1 + 16 * N_) * D_ + d0];
            a2.u = *(const uint4*)&Opart[(r1 + 32 * N_) * D_ + d0];
            a3.u = *(const uint4*)&Opart[(r1 + 48 * N_) * D_ + d0];
            float w0 = wgt[h][0], w1 = wgt[h][1], w2 = wgt[h][2], w3 = wgt[h][3];
            uint4 mv;
            unsigned* mp = (unsigned*)&mv;
            #pragma unroll
            for (int j = 0; j < 4; ++j) {
                float lo = bf2f(a0.s[2*j]) * w0 + bf2f(a1.s[2*j]) * w1
                         + bf2f(a2.s[2*j]) * w2 + bf2f(a3.s[2*j]) * w3;
                float hi = bf2f(a0.s[2*j+1]) * w0 + bf2f(a1.s[2*j+1]) * w1
                         + bf2f(a2.s[2*j+1]) * w2 + bf2f(a3.s[2*j+1]) * w3;
                mp[j] = pack2(lo, hi);
            }
            *(uint4*)&As[srow * 40 + scb] = mv;
            *(uint4*)&Bs[srow * 40 + scb] = *(const uint4*)&wb[(size_t)(o0 + srow) * 256 + k0 + scb];
        }
        __syncthreads();
        bf16x8 a = ld_frag(&As[(wave * 16 + l16) * 40 + quad * 8]);
        #pragma unroll
        for (int nt = 0; nt < 4; ++nt) {
            bf16x8 b = ld_frag(&Bs[(nt * 16 + l16) * 40 + quad * 8]);
            acc[nt] = __builtin_amdgcn_mfma_f32_16x16x32_bf16(a, b, acc[nt], 0, 0, 0);
        }
    }

    float bv[4];
    #pragma unroll
    for (int nt = 0; nt < 4; ++nt) bv[nt] = bias[o0 + nt * 16 + l16];
    #pragma unroll
    for (int r = 0; r < 4; ++r) {
        int m = m0 + wave * 16 + quad * 4 + r;
        #pragma unroll
        for (int nt = 0; nt < 4; ++nt)
            out[(size_t)m * 256 + o0 + nt * 16 + l16] = acc[nt][r] + bv[nt];
    }
}

extern "C" void kernel_launch(void* const* d_in, const int* in_sizes, int n_in,
                              void* d_out, int out_size, void* d_ws, size_t ws_size,
                              hipStream_t stream) {
    const float* x       = (const float*)d_in[0];
    const float* Rm      = (const float*)d_in[1];
    const float* Pm      = (const float*)d_in[2];
    const float* qkv_w   = (const float*)d_in[3];
    const float* qkv_b   = (const float*)d_in[4];
    const float* proj_w  = (const float*)d_in[5];
    const float* proj_b  = (const float*)d_in[6];
    const float* pos_scl = (const float*)d_in[7];
    float* out = (float*)d_out;

    const size_t NE = (size_t)B_ * H_ * N_ * D_;   // 2,097,152
    unsigned short* opart = (unsigned short*)d_ws; // 4 partials = 16 MB
    unsigned short* qb    = opart + 4 * NE;        // 4 MB each
    unsigned short* kb    = qb   + NE;
    unsigned short* vtb   = kb   + NE;
    float*          mlb   = (float*)(vtb + NE);    // 4*16*2048 float2 = 1 MB
    unsigned short* eb    = (unsigned short*)(mlb + (size_t)4 * 16 * N_ * 2); // 64 KB
    unsigned short* wqb   = eb  + 2048 * 16;       // 384 KB
    unsigned short* wpb   = wqb + 768 * 256;       // 128 KB
    unsigned short* xb    = opart;                 // alias: xb dead before attn writes

    cvt_kernel<<<1160, 256, 0, stream>>>(x, qkv_w, proj_w, Pm, xb, wqb, wpb, eb);
    qkv_gemm<<<dim3(64, 6), 256, 0, stream>>>(xb, wqb, qkv_b, qb, kb, vtb);
    attn_kernel<<<dim3(32, 16, 4), 256, 0, stream>>>(qb, kb, vtb, eb, Rm, Pm, pos_scl, opart, mlb);
    proj_gemm<<<dim3(128, 4), 256, 0, stream>>>(opart, mlb, wpb, proj_b, out);
}

// Round 5
// 136.186 us; speedup vs baseline: 1.1381x; 1.0561x over previous
//
#include <hip/hip_runtime.h>
#include <hip/hip_bf16.h>

#define B_ 4
#define N_ 2048
#define C_ 256
#define H_ 4
#define D_ 64

typedef __attribute__((ext_vector_type(8))) short bf16x8;
typedef __attribute__((ext_vector_type(4))) float f32x4;

#define LOG2E 1.4426950408889634f

// f32 -> bf16 round-to-nearest-even (scalar)
static __device__ inline unsigned short f2bf(float f) {
    unsigned u = __builtin_bit_cast(unsigned, f);
    unsigned r = (u + 0x7fffu + ((u >> 16) & 1u)) >> 16;
    return (unsigned short)r;
}
static __device__ inline float bf2f(unsigned short h) {
    unsigned u = ((unsigned)h) << 16;
    return __builtin_bit_cast(float, u);
}
// packed pair f32 -> bf16x2
static __device__ inline unsigned pack2(float a, float b) {
    __hip_bfloat162 h = __float22bfloat162_rn(make_float2(a, b));
    unsigned u;
    __builtin_memcpy(&u, &h, 4);
    return u;
}
static __device__ inline bf16x8 ld_frag(const unsigned short* p) {
    return __builtin_bit_cast(bf16x8, *(const uint4*)p);
}
// async global->LDS DMA, 16B per lane, dest = ldsbase + lane*16
static __device__ inline void gload_lds16(const unsigned short* g, unsigned short* l) {
    __builtin_amdgcn_global_load_lds(
        (const __attribute__((address_space(1))) unsigned int*)(g),
        (__attribute__((address_space(3))) unsigned int*)(l),
        16, 0, 0);
}
// fmax with a DPP-permuted copy (VALU-latency cross-lane, 16-lane row scope)
template<int CTRL>
static __device__ inline float fmax_dpp(float x) {
    int yi = __builtin_amdgcn_update_dpp(0, __builtin_bit_cast(int, x),
                                         CTRL, 0xf, 0xf, true);
    return fmaxf(x, __builtin_bit_cast(float, yi));
}

// ---------------- cvt prepass: x / qkv_w / proj_w -> bf16; Pm -> ext table ----
// ext row (16 shorts) per key n: [ph0,ph1,ph2,pl0,pl1,pl2,ph0,ph1 | ph2,0,..,0]
__global__ __launch_bounds__(256) void cvt_kernel(
    const float* __restrict__ x, const float* __restrict__ qkv_w,
    const float* __restrict__ proj_w, const float* __restrict__ Pm,
    unsigned short* __restrict__ xb, unsigned short* __restrict__ wqb,
    unsigned short* __restrict__ wpb, unsigned short* __restrict__ eb)
{
    const int bid = blockIdx.x, tid = threadIdx.x;
    if (bid >= 1152) {
        const int n = (bid - 1152) * 256 + tid;
        const float* pp = Pm + n * 3;
        float p0 = pp[0], p1 = pp[1], p2 = pp[2];
        unsigned u0 = f2bf(p0), u1 = f2bf(p1), u2 = f2bf(p2);
        unsigned v0 = f2bf(p0 - bf2f((unsigned short)u0));
        unsigned v1 = f2bf(p1 - bf2f((unsigned short)u1));
        unsigned v2 = f2bf(p2 - bf2f((unsigned short)u2));
        uint4 lo, hi;
        lo.x = u0 | (u1 << 16); lo.y = u2 | (v0 << 16);
        lo.z = v1 | (v2 << 16); lo.w = u0 | (u1 << 16);
        hi.x = u2; hi.y = 0u; hi.z = 0u; hi.w = 0u;
        *(uint4*)&eb[n * 16 + 0] = lo;
        *(uint4*)&eb[n * 16 + 8] = hi;
        return;
    }
    const float* s; unsigned short* d; int i;
    if (bid < 1024)      { s = x;      d = xb;  i = (bid * 256 + tid) * 8; }
    else if (bid < 1120) { s = qkv_w;  d = wqb; i = ((bid - 1024) * 256 + tid) * 8; }
    else                 { s = proj_w; d = wpb; i = ((bid - 1120) * 256 + tid) * 8; }
    float4 a = *(const float4*)(s + i);
    float4 b = *(const float4*)(s + i + 4);
    uint4 u;
    u.x = pack2(a.x, a.y); u.y = pack2(a.z, a.w);
    u.z = pack2(b.x, b.y); u.w = pack2(b.z, b.w);
    *(uint4*)(d + i) = u;
}

// ---------------- QKV GEMM: bf16, 128x128 tile, 4 waves 2x2, BK=32 ----------
// Q pre-scaled by 0.125*log2e. V written transposed+permuted:
// vt[bh][d][n_perm], perm within 64-block: p = 4*(n&15)+((n>>4)&3).
__global__ __launch_bounds__(256) void qkv_gemm(
    const unsigned short* __restrict__ xb, const unsigned short* __restrict__ wb,
    const float* __restrict__ bias, unsigned short* __restrict__ qb,
    unsigned short* __restrict__ kb, unsigned short* __restrict__ vt)
{
    __shared__ __align__(16) unsigned short As[128 * 40];
    __shared__ __align__(16) unsigned short Bs[128 * 40];
    const int m0 = blockIdx.x * 128, o0 = blockIdx.y * 128;
    const int tid = threadIdx.x;
    const int wave = tid >> 6, lane = tid & 63, quad = lane >> 4, l16 = lane & 15;
    const int wy = wave >> 1, wx = wave & 1;

    f32x4 acc[4][4];
    #pragma unroll
    for (int i = 0; i < 4; ++i)
        #pragma unroll
        for (int j = 0; j < 4; ++j) acc[i][j] = (f32x4){0.f, 0.f, 0.f, 0.f};

    const int srow = tid >> 1, soff = (tid & 1) * 16;   // 128 rows x 32 cols staging

    for (int k0 = 0; k0 < 256; k0 += 32) {
        __syncthreads();
        {
            const unsigned short* sa = &xb[(size_t)(m0 + srow) * 256 + k0 + soff];
            const unsigned short* sb = &wb[(size_t)(o0 + srow) * 256 + k0 + soff];
            *(uint4*)&As[srow * 40 + soff + 0] = *(const uint4*)(sa + 0);
            *(uint4*)&As[srow * 40 + soff + 8] = *(const uint4*)(sa + 8);
            *(uint4*)&Bs[srow * 40 + soff + 0] = *(const uint4*)(sb + 0);
            *(uint4*)&Bs[srow * 40 + soff + 8] = *(const uint4*)(sb + 8);
        }
        __syncthreads();
        bf16x8 a[4], b[4];
        #pragma unroll
        for (int mt = 0; mt < 4; ++mt) a[mt] = ld_frag(&As[(wy * 64 + mt * 16 + l16) * 40 + quad * 8]);
        #pragma unroll
        for (int nt = 0; nt < 4; ++nt) b[nt] = ld_frag(&Bs[(wx * 64 + nt * 16 + l16) * 40 + quad * 8]);
        #pragma unroll
        for (int mt = 0; mt < 4; ++mt)
            #pragma unroll
            for (int nt = 0; nt < 4; ++nt)
                acc[mt][nt] = __builtin_amdgcn_mfma_f32_16x16x32_bf16(a[mt], b[nt], acc[mt][nt], 0, 0, 0);
    }

    const int sec = o0 + wx * 64;            // this wave's 64 output cols
    const int three = sec >> 8;
    const int h = (sec >> 6) & 3;
    const int b = m0 >> 11;
    float bv[4];
    #pragma unroll
    for (int nt = 0; nt < 4; ++nt) bv[nt] = bias[sec + nt * 16 + l16];

    if (three == 2) {
        // V: n = m0 + wy*64 + mt*16 + quad*4 + r; p = 16*quad + 4*r + mt (mt fast)
        const int n64 = (m0 + wy * 64) & 2047;
        const size_t bh64 = ((size_t)b * H_ + h) * 64;
        #pragma unroll
        for (int nt = 0; nt < 4; ++nt) {
            int d = nt * 16 + l16;
            #pragma unroll
            for (int r = 0; r < 4; ++r) {
                ushort4 v;
                v.x = f2bf(acc[0][nt][r] + bv[nt]);
                v.y = f2bf(acc[1][nt][r] + bv[nt]);
                v.z = f2bf(acc[2][nt][r] + bv[nt]);
                v.w = f2bf(acc[3][nt][r] + bv[nt]);
                *(ushort4*)&vt[(bh64 + d) * N_ + n64 + 16 * quad + 4 * r] = v;
            }
        }
    } else {
        unsigned short* dst = (three == 0) ? qb : kb;
        float sc = (three == 0) ? (0.125f * LOG2E) : 1.0f;
        #pragma unroll
        for (int mt = 0; mt < 4; ++mt)
            #pragma unroll
            for (int r = 0; r < 4; ++r) {
                int n = (m0 + wy * 64 + mt * 16 + quad * 4 + r) & 2047;
                size_t rowbase = (((size_t)b * H_ + h) * N_ + n) * D_;
                #pragma unroll
                for (int nt = 0; nt < 4; ++nt)
                    dst[rowbase + nt * 16 + l16] = f2bf((acc[mt][nt][r] + bv[nt]) * sc);
            }
    }
}

// ---------------- Flash attention: split-K x4, 2-tile software pipeline ------
// Per iteration (one 64-key tile, ONE barrier): softmax+PV act on tile jt-1's
// logits (registers, MFMA latency hidden) while tile jt's QK MFMAs issue.
// Ks/Vs double-buffered (DMA w/ pre-swizzled source), Ps wave-private.
#define LDK 64   // Ks/Vs/Ps row stride in shorts (128 B, 8 slots of 16 B)

__global__ __launch_bounds__(256) void attn_kernel(
    const unsigned short* __restrict__ qb, const unsigned short* __restrict__ kb,
    const unsigned short* __restrict__ vt, const unsigned short* __restrict__ eb,
    const float* __restrict__ Rm, const float* __restrict__ Pm,
    const float* __restrict__ ps_ptr,
    unsigned short* __restrict__ Opart, float* __restrict__ ml)
{
    __shared__ __align__(16) unsigned short Ks[2][64 * LDK]; // 16 KB
    __shared__ __align__(16) unsigned short Vs[2][64 * LDK]; // 16 KB
    __shared__ __align__(16) unsigned short Ps[64 * LDK];    // 8 KB

    const int bh = blockIdx.y;
    const int b = bh >> 2;
    const int i0 = blockIdx.x * 64;
    const int split = blockIdx.z;
    const int tid = threadIdx.x;
    const int wave = tid >> 6, lane = tid & 63;
    const int quad = lane >> 4, l16 = lane & 15;
    const int x7 = l16 & 7;
    const float ps = ps_ptr[0];

    const size_t base = (size_t)bh * N_ * D_;
    const unsigned short* qg = qb + base;
    const unsigned short* kg = kb + base;
    const unsigned short* vg = vt + base;   // rows of length N_

    const int jbeg = split * (N_ / 4);
    // NT = (N_/4)/64 = 8 tiles, hard-coded into the 3x2+1 step schedule below.

    // ---- DMA source pointers (pre-swizzled), advanced per tile ----
    const int rl = lane >> 3, sl = lane & 7;          // 8 rows x 8 slots per issue
    const int swz = (sl ^ rl) * 8;
    const unsigned short* kq = kg + (size_t)(jbeg + wave * 16 + rl) * D_ + swz;
    const unsigned short* vq = vg + (size_t)(wave * 16 + rl) * N_ + jbeg + swz;
    const unsigned short* ep = eb + (size_t)(jbeg + l16) * 16 + (quad & 1) * 8;

    auto ISSUE_K = [&](int nb) {
        unsigned short* kd = &Ks[nb][(wave * 16) * LDK];
        gload_lds16(kq,          kd);
        gload_lds16(kq + 8 * D_, kd + 8 * LDK);
        kq += 64 * D_;
    };
    auto ISSUE_V = [&](int nb) {
        unsigned short* vd = &Vs[nb][(wave * 16) * LDK];
        gload_lds16(vq,          vd);
        gload_lds16(vq + 8 * N_, vd + 8 * LDK);
        vq += 64;
    };
    auto LOAD_E = [&](bf16x8 (&e)[4]) {
        #pragma unroll
        for (int t = 0; t < 4; ++t) e[t] = ld_frag(ep + t * 256);
        ep += 64 * 16;
    };

    // prologue: K(0) DMA + ext(0) regs
    ISSUE_K(0);
    bf16x8 eA[4], eB[4];
    LOAD_E(eA);

    // Q A-fragments (pre-scaled by 0.125*log2e)
    const int qrow = i0 + wave * 16 + l16;
    bf16x8 aq[3];
    #pragma unroll
    for (int ks = 0; ks < 2; ++ks)
        aq[ks] = ld_frag(&qg[(size_t)qrow * D_ + ks * 32 + quad * 8]);

    // A-side bias ext: a = ps*log2e*(R_b @ P_qrow), hi/lo split
    {
        float p0 = Pm[qrow * 3 + 0], p1 = Pm[qrow * 3 + 1], p2 = Pm[qrow * 3 + 2];
        float sc = ps * LOG2E;
        unsigned short ah[3], al[3];
        #pragma unroll
        for (int c = 0; c < 3; ++c) {
            float a = (Rm[b * 9 + c * 3 + 0] * p0 + Rm[b * 9 + c * 3 + 1] * p1
                     + Rm[b * 9 + c * 3 + 2] * p2) * sc;
            ah[c] = f2bf(a);
            al[c] = f2bf(a - bf2f(ah[c]));
        }
        bf16x8 e = (bf16x8){0,0,0,0,0,0,0,0};
        if (quad == 0) {
            e[0] = (short)ah[0]; e[1] = (short)ah[1]; e[2] = (short)ah[2];
            e[3] = (short)ah[0]; e[4] = (short)ah[1]; e[5] = (short)ah[2];
            e[6] = (short)al[0]; e[7] = (short)al[1];
        } else if (quad == 1) {
            e[0] = (short)al[2];
        }
        aq[2] = e;
    }

    const bf16x8 ones = (bf16x8){0x3F80,0x3F80,0x3F80,0x3F80,0x3F80,0x3F80,0x3F80,0x3F80};

    float m_run = -1e30f;
    f32x4 o_acc[4], lacc;
    #pragma unroll
    for (int t = 0; t < 4; ++t) o_acc[t] = (f32x4){0.f, 0.f, 0.f, 0.f};
    lacc = (f32x4){0.f, 0.f, 0.f, 0.f};

    f32x4 sA[4], sB[4];

    // S (log2-domain logits incl. bias) for the tile in Ks[kb_]
    auto S_COMPUTE = [&](f32x4 (&sc)[4], int kb_, bf16x8 (&ec)[4]) {
        __builtin_amdgcn_s_setprio(1);
        #pragma unroll
        for (int t = 0; t < 4; ++t) {
            const int rb = (l16 + 16 * t) * LDK;
            f32x4 c = {0.f, 0.f, 0.f, 0.f};
            #pragma unroll
            for (int ks = 0; ks < 2; ++ks) {
                bf16x8 bk = ld_frag(&Ks[kb_][rb + (((ks * 4 + quad) ^ x7) * 8)]);
                c = __builtin_amdgcn_mfma_f32_16x16x32_bf16(aq[ks], bk, c, 0, 0, 0);
            }
            c = __builtin_amdgcn_mfma_f32_16x16x32_bf16(aq[2], ec[t], c, 0, 0, 0);
            sc[t] = c;
        }
        __builtin_amdgcn_s_setprio(0);
    };

    // online softmax on a tile's logits (registers) -> Ps (wave-private rows)
    auto SOFTMAX = [&](f32x4 (&s)[4]) {
        float mt[4];
        #pragma unroll
        for (int t = 0; t < 4; ++t)
            mt[t] = fmaxf(fmaxf(s[t][0], s[t][1]), fmaxf(s[t][2], s[t][3]));
        float mx = fmaxf(fmaxf(mt[0], mt[1]), fmaxf(mt[2], mt[3]));
        mx = fmax_dpp<0xB1>(mx);    // quad_perm [1,0,3,2]  (xor 1)
        mx = fmax_dpp<0x4E>(mx);    // quad_perm [2,3,0,1]  (xor 2)
        mx = fmax_dpp<0x124>(mx);   // row_ror:4
        mx = fmax_dpp<0x128>(mx);   // row_ror:8
        if (__any(mx > m_run + 8.0f)) {       // defer-max rescale
            float mnew = fmaxf(m_run, mx);
            float alpha = exp2f(m_run - mnew);
            #pragma unroll
            for (int t = 0; t < 4; ++t)
                #pragma unroll
                for (int r = 0; r < 4; ++r)
                    o_acc[t][r] *= alpha;
            #pragma unroll
            for (int r = 0; r < 4; ++r) lacc[r] *= alpha;
            m_run = mnew;
        }
        #pragma unroll
        for (int r = 0; r < 4; ++r) {
            float p0 = exp2f(s[0][r] - m_run), p1 = exp2f(s[1][r] - m_run);
            float p2 = exp2f(s[2][r] - m_run), p3 = exp2f(s[3][r] - m_run);
            uint2 w;
            w.x = pack2(p0, p1);
            w.y = pack2(p2, p3);
            const int prow = quad * 4 + r;
            *(uint2*)&Ps[(wave * 16 + prow) * LDK
                         + (((l16 >> 1) ^ (prow & 7)) * 8) + (l16 & 1) * 4] = w;
        }
    };

    // O += P V; l += P . 1 (ones-MFMA); reads Vs[vb_]
    auto PV = [&](int vb_) {
        __builtin_amdgcn_s_setprio(1);
        #pragma unroll
        for (int ks = 0; ks < 2; ++ks) {
            bf16x8 ap = ld_frag(&Ps[(wave * 16 + l16) * LDK
                                    + (((ks * 4 + quad) ^ x7) * 8)]);
            #pragma unroll
            for (int t = 0; t < 4; ++t) {
                bf16x8 bv = ld_frag(&Vs[vb_][(l16 + 16 * t) * LDK
                                             + (((ks * 4 + quad) ^ x7) * 8)]);
                o_acc[t] = __builtin_amdgcn_mfma_f32_16x16x32_bf16(ap, bv, o_acc[t], 0, 0, 0);
            }
            lacc = __builtin_amdgcn_mfma_f32_16x16x32_bf16(ap, ones, lacc, 0, 0, 0);
        }
        __builtin_amdgcn_s_setprio(0);
    };

    // pipeline step for tile jt (cur = jt&1): softmax+PV of tile jt-1 overlap
    // the QK MFMAs of tile jt; single barrier per tile.
    auto STEP = [&](int cur, bool more, f32x4 (&snew)[4], f32x4 (&sold)[4],
                    bf16x8 (&euse)[4], bf16x8 (&eload)[4]) {
        asm volatile("s_waitcnt vmcnt(0)" ::: "memory");
        __builtin_amdgcn_s_barrier();
        __builtin_amdgcn_sched_barrier(0);
        if (more) ISSUE_K(cur ^ 1);   // K(jt+1)
        ISSUE_V(cur);                 // V(jt)
        SOFTMAX(sold);                // tile jt-1 -> Ps
        S_COMPUTE(snew, cur, euse);   // tile jt logits (hides Ps lgkm + fills matrix pipe)
        if (more) LOAD_E(eload);      // ext(jt+1)
        PV(cur ^ 1);                  // tile jt-1: Ps x Vs[(jt-1)&1]
    };

    // --- prologue step (tile 0): no softmax/PV yet ---
    asm volatile("s_waitcnt vmcnt(0)" ::: "memory");
    __builtin_amdgcn_s_barrier();
    __builtin_amdgcn_sched_barrier(0);
    ISSUE_K(1);      // K(1)
    ISSUE_V(0);      // V(0)
    S_COMPUTE(sA, 0, eA);
    LOAD_E(eB);      // ext(1)

    // --- tiles 1..7 (NT=8): 3 pairs + 1 tail ---
    #pragma unroll 1
    for (int it = 0; it < 3; ++it) {
        STEP(1, true, sB, sA, eB, eA);
        STEP(0, true, sA, sB, eA, eB);
    }
    STEP(1, false, sB, sA, eB, eA);

    // --- epilogue: finish tile 7 ---
    asm volatile("s_waitcnt vmcnt(0)" ::: "memory");
    __builtin_amdgcn_s_barrier();
    __builtin_amdgcn_sched_barrier(0);
    SOFTMAX(sB);
    PV(1);

    // store unnormalized partial O (bf16) + (m,l) per row
    const size_t pbase = (size_t)(split * 16 + bh) * N_;
    #pragma unroll
    for (int r = 0; r < 4; ++r) {
        int row = i0 + wave * 16 + quad * 4 + r;
        #pragma unroll
        for (int t = 0; t < 4; ++t)
            Opart[(pbase + row) * D_ + l16 + 16 * t] = f2bf(o_acc[t][r]);
        if (l16 == 0) {
            float2* mlp = (float2*)ml;
            mlp[pbase + row] = make_float2(m_run, lacc[r]);
        }
    }
}

// ---------------- Output projection: fused 4-way merge, hoisted weights ------
// 64x64 tile, 4 waves on M; bf16 weights from cvt prepass.
__global__ __launch_bounds__(256) void proj_gemm(
    const unsigned short* __restrict__ Opart, const float* __restrict__ ml,
    const unsigned short* __restrict__ wb, const float* __restrict__ bias,
    float* __restrict__ out)
{
    __shared__ __align__(16) unsigned short As[64 * 40];
    __shared__ __align__(16) unsigned short Bs[64 * 40];
    const int m0 = blockIdx.x * 64, o0 = blockIdx.y * 64;
    const int tid = threadIdx.x;
    const int wave = tid >> 6, lane = tid & 63, quad = lane >> 4, l16 = lane & 15;
    const float2* mlp = (const float2*)ml;

    const int srow = tid >> 2, scb = (tid & 3) * 8;
    const int sm = m0 + srow, sb = sm >> 11, sn = sm & 2047;

    // hoist 4-way merge weights per h
    float wgt[4][4];
    #pragma unroll
    for (int h = 0; h < 4; ++h) {
        size_t r1 = (size_t)(sb * 4 + h) * N_ + sn;
        float2 m0v = mlp[r1], m1v = mlp[r1 + 16 * N_];
        float2 m2v = mlp[r1 + 32 * N_], m3v = mlp[r1 + 48 * N_];
        float mm = fmaxf(fmaxf(m0v.x, m1v.x), fmaxf(m2v.x, m3v.x));
        float w0 = exp2f(m0v.x - mm), w1 = exp2f(m1v.x - mm);
        float w2 = exp2f(m2v.x - mm), w3 = exp2f(m3v.x - mm);
        float inv = 1.f / (m0v.y * w0 + m1v.y * w1 + m2v.y * w2 + m3v.y * w3);
        wgt[h][0] = w0 * inv; wgt[h][1] = w1 * inv;
        wgt[h][2] = w2 * inv; wgt[h][3] = w3 * inv;
    }

    f32x4 acc[4];
    #pragma unroll
    for (int j = 0; j < 4; ++j) acc[j] = (f32x4){0.f, 0.f, 0.f, 0.f};

    for (int k0 = 0; k0 < 256; k0 += 32) {
        const int h = k0 >> 6;
        const int d0 = (k0 & 63) + scb;
        __syncthreads();
        {   // A: 4-way merge -> bf16; B: bf16 copy
            size_t r1 = (size_t)(sb * 4 + h) * N_ + sn;
            union { uint4 u; unsigned short s[8]; } a0, a1, a2, a3;
            a0.u = *(const uint4*)&Opart[(r1 +  0 * N_) * D_ + d0];
            a1.u = *(const uint4*)&Opart[(r1 + 16 * N_) * D_ + d0];
            a2.u = *(const uint4*)&Opart[(r1 + 32 * N_) * D_ + d0];
            a3.u = *(const uint4*)&Opart[(r1 + 48 * N_) * D_ + d0];
            float w0 = wgt[h][0], w1 = wgt[h][1], w2 = wgt[h][2], w3 = wgt[h][3];
            uint4 mv;
            unsigned* mp = (unsigned*)&mv;
            #pragma unroll
            for (int j = 0; j < 4; ++j) {
                float lo = bf2f(a0.s[2*j]) * w0 + bf2f(a1.s[2*j]) * w1
                         + bf2f(a2.s[2*j]) * w2 + bf2f(a3.s[2*j]) * w3;
                float hi = bf2f(a0.s[2*j+1]) * w0 + bf2f(a1.s[2*j+1]) * w1
                         + bf2f(a2.s[2*j+1]) * w2 + bf2f(a3.s[2*j+1]) * w3;
                mp[j] = pack2(lo, hi);
            }
            *(uint4*)&As[srow * 40 + scb] = mv;
            *(uint4*)&Bs[srow * 40 + scb] = *(const uint4*)&wb[(size_t)(o0 + srow) * 256 + k0 + scb];
        }
        __syncthreads();
        bf16x8 a = ld_frag(&As[(wave * 16 + l16) * 40 + quad * 8]);
        #pragma unroll
        for (int nt = 0; nt < 4; ++nt) {
            bf16x8 b = ld_frag(&Bs[(nt * 16 + l16) * 40 + quad * 8]);
            acc[nt] = __builtin_amdgcn_mfma_f32_16x16x32_bf16(a, b, acc[nt], 0, 0, 0);
        }
    }

    float bv[4];
    #pragma unroll
    for (int nt = 0; nt < 4; ++nt) bv[nt] = bias[o0 + nt * 16 + l16];
    #pragma unroll
    for (int r = 0; r < 4; ++r) {
        int m = m0 + wave * 16 + quad * 4 + r;
        #pragma unroll
        for (int nt = 0; nt < 4; ++nt)
            out[(size_t)m * 256 + o0 + nt * 16 + l16] = acc[nt][r] + bv[nt];
    }
}

extern "C" void kernel_launch(void* const* d_in, const int* in_sizes, int n_in,
                              void* d_out, int out_size, void* d_ws, size_t ws_size,
                              hipStream_t stream) {
    const float* x       = (const float*)d_in[0];
    const float* Rm      = (const float*)d_in[1];
    const float* Pm      = (const float*)d_in[2];
    const float* qkv_w   = (const float*)d_in[3];
    const float* qkv_b   = (const float*)d_in[4];
    const float* proj_w  = (const float*)d_in[5];
    const float* proj_b  = (const float*)d_in[6];
    const float* pos_scl = (const float*)d_in[7];
    float* out = (float*)d_out;

    const size_t NE = (size_t)B_ * H_ * N_ * D_;   // 2,097,152
    unsigned short* opart = (unsigned short*)d_ws; // 4 partials = 16 MB
    unsigned short* qb    = opart + 4 * NE;        // 4 MB each
    unsigned short* kb    = qb   + NE;
    unsigned short* vtb   = kb   + NE;
    float*          mlb   = (float*)(vtb + NE);    // 4*16*2048 float2 = 1 MB
    unsigned short* eb    = (unsigned short*)(mlb + (size_t)4 * 16 * N_ * 2); // 64 KB
    unsigned short* wqb   = eb  + 2048 * 16;       // 384 KB
    unsigned short* wpb   = wqb + 768 * 256;       // 128 KB
    unsigned short* xb    = opart;                 // alias: xb dead before attn writes

    cvt_kernel<<<1160, 256, 0, stream>>>(x, qkv_w, proj_w, Pm, xb, wqb, wpb, eb);
    qkv_gemm<<<dim3(64, 6), 256, 0, stream>>>(xb, wqb, qkv_b, qb, kb, vtb);
    attn_kernel<<<dim3(32, 16, 4), 256, 0, stream>>>(qb, kb, vtb, eb, Rm, Pm, pos_scl, opart, mlb);
    proj_gemm<<<dim3(128, 4), 256, 0, stream>>>(opart, mlb, wpb, proj_b, out);
}

// Round 6
// 134.281 us; speedup vs baseline: 1.1543x; 1.0142x over previous
//
#include <hip/hip_runtime.h>
#include <hip/hip_bf16.h>

#define B_ 4
#define N_ 2048
#define C_ 256
#define H_ 4
#define D_ 64

typedef __attribute__((ext_vector_type(8))) short bf16x8;
typedef __attribute__((ext_vector_type(4))) float f32x4;

#define LOG2E 1.4426950408889634f

// f32 -> bf16 round-to-nearest-even (scalar)
static __device__ inline unsigned short f2bf(float f) {
    unsigned u = __builtin_bit_cast(unsigned, f);
    unsigned r = (u + 0x7fffu + ((u >> 16) & 1u)) >> 16;
    return (unsigned short)r;
}
static __device__ inline float bf2f(unsigned short h) {
    unsigned u = ((unsigned)h) << 16;
    return __builtin_bit_cast(float, u);
}
// packed pair f32 -> bf16x2
static __device__ inline unsigned pack2(float a, float b) {
    __hip_bfloat162 h = __float22bfloat162_rn(make_float2(a, b));
    unsigned u;
    __builtin_memcpy(&u, &h, 4);
    return u;
}
static __device__ inline bf16x8 ld_frag(const unsigned short* p) {
    return __builtin_bit_cast(bf16x8, *(const uint4*)p);
}
// async global->LDS DMA, 16B per lane, dest = ldsbase + lane*16
static __device__ inline void gload_lds16(const unsigned short* g, unsigned short* l) {
    __builtin_amdgcn_global_load_lds(
        (const __attribute__((address_space(1))) unsigned int*)(g),
        (__attribute__((address_space(3))) unsigned int*)(l),
        16, 0, 0);
}
// fmax with a DPP-permuted copy (VALU-latency cross-lane, 16-lane row scope)
template<int CTRL>
static __device__ inline float fmax_dpp(float x) {
    int yi = __builtin_amdgcn_update_dpp(0, __builtin_bit_cast(int, x),
                                         CTRL, 0xf, 0xf, true);
    return fmaxf(x, __builtin_bit_cast(float, yi));
}

// ---------------- cvt prepass: x / qkv_w / proj_w -> bf16; Pm -> ext table ----
// ext row (16 shorts) per key n: [ph0,ph1,ph2,pl0,pl1,pl2,ph0,ph1 | ph2,0,..,0]
__global__ __launch_bounds__(256) void cvt_kernel(
    const float* __restrict__ x, const float* __restrict__ qkv_w,
    const float* __restrict__ proj_w, const float* __restrict__ Pm,
    unsigned short* __restrict__ xb, unsigned short* __restrict__ wqb,
    unsigned short* __restrict__ wpb, unsigned short* __restrict__ eb)
{
    const int bid = blockIdx.x, tid = threadIdx.x;
    if (bid >= 1152) {
        const int n = (bid - 1152) * 256 + tid;
        const float* pp = Pm + n * 3;
        float p0 = pp[0], p1 = pp[1], p2 = pp[2];
        unsigned u0 = f2bf(p0), u1 = f2bf(p1), u2 = f2bf(p2);
        unsigned v0 = f2bf(p0 - bf2f((unsigned short)u0));
        unsigned v1 = f2bf(p1 - bf2f((unsigned short)u1));
        unsigned v2 = f2bf(p2 - bf2f((unsigned short)u2));
        uint4 lo, hi;
        lo.x = u0 | (u1 << 16); lo.y = u2 | (v0 << 16);
        lo.z = v1 | (v2 << 16); lo.w = u0 | (u1 << 16);
        hi.x = u2; hi.y = 0u; hi.z = 0u; hi.w = 0u;
        *(uint4*)&eb[n * 16 + 0] = lo;
        *(uint4*)&eb[n * 16 + 8] = hi;
        return;
    }
    const float* s; unsigned short* d; int i;
    if (bid < 1024)      { s = x;      d = xb;  i = (bid * 256 + tid) * 8; }
    else if (bid < 1120) { s = qkv_w;  d = wqb; i = ((bid - 1024) * 256 + tid) * 8; }
    else                 { s = proj_w; d = wpb; i = ((bid - 1120) * 256 + tid) * 8; }
    float4 a = *(const float4*)(s + i);
    float4 b = *(const float4*)(s + i + 4);
    uint4 u;
    u.x = pack2(a.x, a.y); u.y = pack2(a.z, a.w);
    u.z = pack2(b.x, b.y); u.w = pack2(b.z, b.w);
    *(uint4*)(d + i) = u;
}

// ---------------- QKV GEMM: bf16, 128x128 tile, BK=64, DMA double-buffer -----
// global_load_lds with pre-swizzled source (slot ^= row&7), one barrier/iter.
// Q pre-scaled by 0.125*log2e. V written transposed+permuted:
// vt[bh][d][n_perm], perm within 64-block: p = 4*(n&15)+((n>>4)&3).
__global__ __launch_bounds__(256) void qkv_gemm(
    const unsigned short* __restrict__ xb, const unsigned short* __restrict__ wb,
    const float* __restrict__ bias, unsigned short* __restrict__ qb,
    unsigned short* __restrict__ kb, unsigned short* __restrict__ vt)
{
    __shared__ __align__(16) unsigned short As[2][128 * 64]; // 32 KB
    __shared__ __align__(16) unsigned short Bs[2][128 * 64]; // 32 KB
    const int m0 = blockIdx.x * 128, o0 = blockIdx.y * 128;
    const int tid = threadIdx.x;
    const int wave = tid >> 6, lane = tid & 63, quad = lane >> 4, l16 = lane & 15;
    const int wy = wave >> 1, wx = wave & 1;
    const int x7 = l16 & 7;
    const int rl = lane >> 3, sl = lane & 7;      // 8 rows x 8 slots per DMA issue
    const int swz = (sl ^ rl) * 8;

    const unsigned short* aq0 = &xb[(size_t)(m0 + 32 * wave + rl) * 256 + swz];
    const unsigned short* bq0 = &wb[(size_t)(o0 + 32 * wave + rl) * 256 + swz];

    auto ISSUE = [&](int buf, int k0) {
        unsigned short* ad = &As[buf][(32 * wave) * 64];
        unsigned short* bd = &Bs[buf][(32 * wave) * 64];
        #pragma unroll
        for (int i = 0; i < 4; ++i) {
            gload_lds16(aq0 + (size_t)(8 * i) * 256 + k0, ad + (8 * i) * 64);
            gload_lds16(bq0 + (size_t)(8 * i) * 256 + k0, bd + (8 * i) * 64);
        }
    };

    f32x4 acc[4][4];
    #pragma unroll
    for (int i = 0; i < 4; ++i)
        #pragma unroll
        for (int j = 0; j < 4; ++j) acc[i][j] = (f32x4){0.f, 0.f, 0.f, 0.f};

    ISSUE(0, 0);   // prologue: tile 0 in flight

    #pragma unroll
    for (int t = 0; t < 4; ++t) {
        const int cur = t & 1;
        asm volatile("s_waitcnt vmcnt(0)" ::: "memory");   // tile t landed
        __builtin_amdgcn_s_barrier();
        __builtin_amdgcn_sched_barrier(0);
        if (t < 3) ISSUE(cur ^ 1, (t + 1) * 64);           // next tile in flight
        __builtin_amdgcn_s_setprio(1);
        #pragma unroll
        for (int ks = 0; ks < 2; ++ks) {
            bf16x8 a[4], b[4];
            #pragma unroll
            for (int mt = 0; mt < 4; ++mt)
                a[mt] = ld_frag(&As[cur][(wy * 64 + mt * 16 + l16) * 64
                                         + (((ks * 4 + quad) ^ x7) * 8)]);
            #pragma unroll
            for (int nt = 0; nt < 4; ++nt)
                b[nt] = ld_frag(&Bs[cur][(wx * 64 + nt * 16 + l16) * 64
                                         + (((ks * 4 + quad) ^ x7) * 8)]);
            #pragma unroll
            for (int mt = 0; mt < 4; ++mt)
                #pragma unroll
                for (int nt = 0; nt < 4; ++nt)
                    acc[mt][nt] = __builtin_amdgcn_mfma_f32_16x16x32_bf16(a[mt], b[nt], acc[mt][nt], 0, 0, 0);
        }
        __builtin_amdgcn_s_setprio(0);
    }

    const int sec = o0 + wx * 64;            // this wave's 64 output cols
    const int three = sec >> 8;
    const int h = (sec >> 6) & 3;
    const int b = m0 >> 11;
    float bv[4];
    #pragma unroll
    for (int nt = 0; nt < 4; ++nt) bv[nt] = bias[sec + nt * 16 + l16];

    if (three == 2) {
        // V: n = m0 + wy*64 + mt*16 + quad*4 + r; p = 16*quad + 4*r + mt (mt fast)
        const int n64 = (m0 + wy * 64) & 2047;
        const size_t bh64 = ((size_t)b * H_ + h) * 64;
        #pragma unroll
        for (int nt = 0; nt < 4; ++nt) {
            int d = nt * 16 + l16;
            #pragma unroll
            for (int r = 0; r < 4; ++r) {
                ushort4 v;
                v.x = f2bf(acc[0][nt][r] + bv[nt]);
                v.y = f2bf(acc[1][nt][r] + bv[nt]);
                v.z = f2bf(acc[2][nt][r] + bv[nt]);
                v.w = f2bf(acc[3][nt][r] + bv[nt]);
                *(ushort4*)&vt[(bh64 + d) * N_ + n64 + 16 * quad + 4 * r] = v;
            }
        }
    } else {
        unsigned short* dst = (three == 0) ? qb : kb;
        float sc = (three == 0) ? (0.125f * LOG2E) : 1.0f;
        #pragma unroll
        for (int mt = 0; mt < 4; ++mt)
            #pragma unroll
            for (int r = 0; r < 4; ++r) {
                int n = (m0 + wy * 64 + mt * 16 + quad * 4 + r) & 2047;
                size_t rowbase = (((size_t)b * H_ + h) * N_ + n) * D_;
                #pragma unroll
                for (int nt = 0; nt < 4; ++nt)
                    dst[rowbase + nt * 16 + l16] = f2bf((acc[mt][nt][r] + bv[nt]) * sc);
            }
    }
}

// ---------------- Flash attention: split-K x4, 2-tile software pipeline ------
// Per iteration (one 64-key tile, ONE barrier): softmax+PV act on tile jt-1's
// logits (registers, MFMA latency hidden) while tile jt's QK MFMAs issue.
// Ks/Vs double-buffered (DMA w/ pre-swizzled source), Ps wave-private.
#define LDK 64   // Ks/Vs/Ps row stride in shorts (128 B, 8 slots of 16 B)

__global__ __launch_bounds__(256) void attn_kernel(
    const unsigned short* __restrict__ qb, const unsigned short* __restrict__ kb,
    const unsigned short* __restrict__ vt, const unsigned short* __restrict__ eb,
    const float* __restrict__ Rm, const float* __restrict__ Pm,
    const float* __restrict__ ps_ptr,
    unsigned short* __restrict__ Opart, float* __restrict__ ml)
{
    __shared__ __align__(16) unsigned short Ks[2][64 * LDK]; // 16 KB
    __shared__ __align__(16) unsigned short Vs[2][64 * LDK]; // 16 KB
    __shared__ __align__(16) unsigned short Ps[64 * LDK];    // 8 KB

    const int bh = blockIdx.y;
    const int b = bh >> 2;
    const int i0 = blockIdx.x * 64;
    const int split = blockIdx.z;
    const int tid = threadIdx.x;
    const int wave = tid >> 6, lane = tid & 63;
    const int quad = lane >> 4, l16 = lane & 15;
    const int x7 = l16 & 7;
    const float ps = ps_ptr[0];

    const size_t base = (size_t)bh * N_ * D_;
    const unsigned short* qg = qb + base;
    const unsigned short* kg = kb + base;
    const unsigned short* vg = vt + base;   // rows of length N_

    const int jbeg = split * (N_ / 4);
    // NT = (N_/4)/64 = 8 tiles, hard-coded into the 3x2+1 step schedule below.

    // ---- DMA source pointers (pre-swizzled), advanced per tile ----
    const int rl = lane >> 3, sl = lane & 7;          // 8 rows x 8 slots per issue
    const int swz = (sl ^ rl) * 8;
    const unsigned short* kq = kg + (size_t)(jbeg + wave * 16 + rl) * D_ + swz;
    const unsigned short* vq = vg + (size_t)(wave * 16 + rl) * N_ + jbeg + swz;
    const unsigned short* ep = eb + (size_t)(jbeg + l16) * 16 + (quad & 1) * 8;

    auto ISSUE_K = [&](int nb) {
        unsigned short* kd = &Ks[nb][(wave * 16) * LDK];
        gload_lds16(kq,          kd);
        gload_lds16(kq + 8 * D_, kd + 8 * LDK);
        kq += 64 * D_;
    };
    auto ISSUE_V = [&](int nb) {
        unsigned short* vd = &Vs[nb][(wave * 16) * LDK];
        gload_lds16(vq,          vd);
        gload_lds16(vq + 8 * N_, vd + 8 * LDK);
        vq += 64;
    };
    auto LOAD_E = [&](bf16x8 (&e)[4]) {
        #pragma unroll
        for (int t = 0; t < 4; ++t) e[t] = ld_frag(ep + t * 256);
        ep += 64 * 16;
    };

    // prologue: K(0) DMA + ext(0) regs
    ISSUE_K(0);
    bf16x8 eA[4], eB[4];
    LOAD_E(eA);

    // Q A-fragments (pre-scaled by 0.125*log2e)
    const int qrow = i0 + wave * 16 + l16;
    bf16x8 aq[3];
    #pragma unroll
    for (int ks = 0; ks < 2; ++ks)
        aq[ks] = ld_frag(&qg[(size_t)qrow * D_ + ks * 32 + quad * 8]);

    // A-side bias ext: a = ps*log2e*(R_b @ P_qrow), hi/lo split
    {
        float p0 = Pm[qrow * 3 + 0], p1 = Pm[qrow * 3 + 1], p2 = Pm[qrow * 3 + 2];
        float sc = ps * LOG2E;
        unsigned short ah[3], al[3];
        #pragma unroll
        for (int c = 0; c < 3; ++c) {
            float a = (Rm[b * 9 + c * 3 + 0] * p0 + Rm[b * 9 + c * 3 + 1] * p1
                     + Rm[b * 9 + c * 3 + 2] * p2) * sc;
            ah[c] = f2bf(a);
            al[c] = f2bf(a - bf2f(ah[c]));
        }
        bf16x8 e = (bf16x8){0,0,0,0,0,0,0,0};
        if (quad == 0) {
            e[0] = (short)ah[0]; e[1] = (short)ah[1]; e[2] = (short)ah[2];
            e[3] = (short)ah[0]; e[4] = (short)ah[1]; e[5] = (short)ah[2];
            e[6] = (short)al[0]; e[7] = (short)al[1];
        } else if (quad == 1) {
            e[0] = (short)al[2];
        }
        aq[2] = e;
    }

    const bf16x8 ones = (bf16x8){0x3F80,0x3F80,0x3F80,0x3F80,0x3F80,0x3F80,0x3F80,0x3F80};

    float m_run = -1e30f;
    f32x4 o_acc[4], lacc;
    #pragma unroll
    for (int t = 0; t < 4; ++t) o_acc[t] = (f32x4){0.f, 0.f, 0.f, 0.f};
    lacc = (f32x4){0.f, 0.f, 0.f, 0.f};

    f32x4 sA[4], sB[4];

    // S (log2-domain logits incl. bias) for the tile in Ks[kb_]
    auto S_COMPUTE = [&](f32x4 (&sc)[4], int kb_, bf16x8 (&ec)[4]) {
        __builtin_amdgcn_s_setprio(1);
        #pragma unroll
        for (int t = 0; t < 4; ++t) {
            const int rb = (l16 + 16 * t) * LDK;
            f32x4 c = {0.f, 0.f, 0.f, 0.f};
            #pragma unroll
            for (int ks = 0; ks < 2; ++ks) {
                bf16x8 bk = ld_frag(&Ks[kb_][rb + (((ks * 4 + quad) ^ x7) * 8)]);
                c = __builtin_amdgcn_mfma_f32_16x16x32_bf16(aq[ks], bk, c, 0, 0, 0);
            }
            c = __builtin_amdgcn_mfma_f32_16x16x32_bf16(aq[2], ec[t], c, 0, 0, 0);
            sc[t] = c;
        }
        __builtin_amdgcn_s_setprio(0);
    };

    // online softmax on a tile's logits (registers) -> Ps (wave-private rows)
    auto SOFTMAX = [&](f32x4 (&s)[4]) {
        float mt[4];
        #pragma unroll
        for (int t = 0; t < 4; ++t)
            mt[t] = fmaxf(fmaxf(s[t][0], s[t][1]), fmaxf(s[t][2], s[t][3]));
        float mx = fmaxf(fmaxf(mt[0], mt[1]), fmaxf(mt[2], mt[3]));
        mx = fmax_dpp<0xB1>(mx);    // quad_perm [1,0,3,2]  (xor 1)
        mx = fmax_dpp<0x4E>(mx);    // quad_perm [2,3,0,1]  (xor 2)
        mx = fmax_dpp<0x124>(mx);   // row_ror:4
        mx = fmax_dpp<0x128>(mx);   // row_ror:8
        if (__any(mx > m_run + 8.0f)) {       // defer-max rescale
            float mnew = fmaxf(m_run, mx);
            float alpha = exp2f(m_run - mnew);
            #pragma unroll
            for (int t = 0; t < 4; ++t)
                #pragma unroll
                for (int r = 0; r < 4; ++r)
                    o_acc[t][r] *= alpha;
            #pragma unroll
            for (int r = 0; r < 4; ++r) lacc[r] *= alpha;
            m_run = mnew;
        }
        #pragma unroll
        for (int r = 0; r < 4; ++r) {
            float p0 = exp2f(s[0][r] - m_run), p1 = exp2f(s[1][r] - m_run);
            float p2 = exp2f(s[2][r] - m_run), p3 = exp2f(s[3][r] - m_run);
            uint2 w;
            w.x = pack2(p0, p1);
            w.y = pack2(p2, p3);
            const int prow = quad * 4 + r;
            *(uint2*)&Ps[(wave * 16 + prow) * LDK
                         + (((l16 >> 1) ^ (prow & 7)) * 8) + (l16 & 1) * 4] = w;
        }
    };

    // O += P V; l += P . 1 (ones-MFMA); reads Vs[vb_]
    auto PV = [&](int vb_) {
        __builtin_amdgcn_s_setprio(1);
        #pragma unroll
        for (int ks = 0; ks < 2; ++ks) {
            bf16x8 ap = ld_frag(&Ps[(wave * 16 + l16) * LDK
                                    + (((ks * 4 + quad) ^ x7) * 8)]);
            #pragma unroll
            for (int t = 0; t < 4; ++t) {
                bf16x8 bv = ld_frag(&Vs[vb_][(l16 + 16 * t) * LDK
                                             + (((ks * 4 + quad) ^ x7) * 8)]);
                o_acc[t] = __builtin_amdgcn_mfma_f32_16x16x32_bf16(ap, bv, o_acc[t], 0, 0, 0);
            }
            lacc = __builtin_amdgcn_mfma_f32_16x16x32_bf16(ap, ones, lacc, 0, 0, 0);
        }
        __builtin_amdgcn_s_setprio(0);
    };

    // pipeline step for tile jt (cur = jt&1): softmax+PV of tile jt-1 overlap
    // the QK MFMAs of tile jt; single barrier per tile.
    auto STEP = [&](int cur, bool more, f32x4 (&snew)[4], f32x4 (&sold)[4],
                    bf16x8 (&euse)[4], bf16x8 (&eload)[4]) {
        asm volatile("s_waitcnt vmcnt(0)" ::: "memory");
        __builtin_amdgcn_s_barrier();
        __builtin_amdgcn_sched_barrier(0);
        if (more) ISSUE_K(cur ^ 1);   // K(jt+1)
        ISSUE_V(cur);                 // V(jt)
        SOFTMAX(sold);                // tile jt-1 -> Ps
        S_COMPUTE(snew, cur, euse);   // tile jt logits (hides Ps lgkm + fills matrix pipe)
        if (more) LOAD_E(eload);      // ext(jt+1)
        PV(cur ^ 1);                  // tile jt-1: Ps x Vs[(jt-1)&1]
    };

    // --- prologue step (tile 0): no softmax/PV yet ---
    asm volatile("s_waitcnt vmcnt(0)" ::: "memory");
    __builtin_amdgcn_s_barrier();
    __builtin_amdgcn_sched_barrier(0);
    ISSUE_K(1);      // K(1)
    ISSUE_V(0);      // V(0)
    S_COMPUTE(sA, 0, eA);
    LOAD_E(eB);      // ext(1)

    // --- tiles 1..7 (NT=8): 3 pairs + 1 tail ---
    #pragma unroll 1
    for (int it = 0; it < 3; ++it) {
        STEP(1, true, sB, sA, eB, eA);
        STEP(0, true, sA, sB, eA, eB);
    }
    STEP(1, false, sB, sA, eB, eA);

    // --- epilogue: finish tile 7 ---
    asm volatile("s_waitcnt vmcnt(0)" ::: "memory");
    __builtin_amdgcn_s_barrier();
    __builtin_amdgcn_sched_barrier(0);
    SOFTMAX(sB);
    PV(1);

    // store unnormalized partial O (bf16) + (m,l) per row
    const size_t pbase = (size_t)(split * 16 + bh) * N_;
    #pragma unroll
    for (int r = 0; r < 4; ++r) {
        int row = i0 + wave * 16 + quad * 4 + r;
        #pragma unroll
        for (int t = 0; t < 4; ++t)
            Opart[(pbase + row) * D_ + l16 + 16 * t] = f2bf(o_acc[t][r]);
        if (l16 == 0) {
            float2* mlp = (float2*)ml;
            mlp[pbase + row] = make_float2(m_run, lacc[r]);
        }
    }
}

// ---------------- Output projection: fused 4-way merge, BK=64, DMA B ---------
// A-merge on reg path with T14 split (loads issued one compute phase early);
// B tile via DMA double-buffer; one barrier per iter; XOR-swizzled LDS.
__global__ __launch_bounds__(256) void proj_gemm(
    const unsigned short* __restrict__ Opart, const float* __restrict__ ml,
    const unsigned short* __restrict__ wb, const float* __restrict__ bias,
    float* __restrict__ out)
{
    __shared__ __align__(16) unsigned short As[2][64 * 64]; // 16 KB
    __shared__ __align__(16) unsigned short Bs[2][64 * 64]; // 16 KB
    const int m0 = blockIdx.x * 64, o0 = blockIdx.y * 64;
    const int tid = threadIdx.x;
    const int wave = tid >> 6, lane = tid & 63, quad = lane >> 4, l16 = lane & 15;
    const int x7 = l16 & 7;
    const int rl = lane >> 3, sl = lane & 7;
    const int swz = (sl ^ rl) * 8;
    const float2* mlp = (const float2*)ml;

    const int srow = tid >> 2, sc16 = (tid & 3) * 16;   // A-merge: row, 16-col chunk
    const int s0 = (tid & 3) * 2;                       // first of 2 LDS slots
    const int sm = m0 + srow, sb = sm >> 11, sn = sm & 2047;

    // hoist 4-way merge weights per h
    float wgt[4][4];
    #pragma unroll
    for (int h = 0; h < 4; ++h) {
        size_t r1 = (size_t)(sb * 4 + h) * N_ + sn;
        float2 m0v = mlp[r1], m1v = mlp[r1 + 16 * N_];
        float2 m2v = mlp[r1 + 32 * N_], m3v = mlp[r1 + 48 * N_];
        float mm = fmaxf(fmaxf(m0v.x, m1v.x), fmaxf(m2v.x, m3v.x));
        float w0 = exp2f(m0v.x - mm), w1 = exp2f(m1v.x - mm);
        float w2 = exp2f(m2v.x - mm), w3 = exp2f(m3v.x - mm);
        float inv = 1.f / (m0v.y * w0 + m1v.y * w1 + m2v.y * w2 + m3v.y * w3);
        wgt[h][0] = w0 * inv; wgt[h][1] = w1 * inv;
        wgt[h][2] = w2 * inv; wgt[h][3] = w3 * inv;
    }

    const unsigned short* bq0 = &wb[(size_t)(o0 + 16 * wave + rl) * 256 + swz];
    auto ISSUE_B = [&](int buf, int k0) {
        unsigned short* bd = &Bs[buf][(16 * wave) * 64];
        gload_lds16(bq0 + k0,           bd);
        gload_lds16(bq0 + 8 * 256 + k0, bd + 8 * 64);
    };

    union U16 { uint4 u; unsigned short s[8]; };
    U16 ar[4][2];   // [split][8-short half] in-flight A sources
    auto LOAD_A = [&](int h) {
        size_t r1 = (size_t)(sb * 4 + h) * N_ + sn;
        #pragma unroll
        for (int s = 0; s < 4; ++s) {
            const unsigned short* p = &Opart[(r1 + (size_t)(16 * s) * N_) * D_ + sc16];
            ar[s][0].u = *(const uint4*)(p);
            ar[s][1].u = *(const uint4*)(p + 8);
        }
    };

    ISSUE_B(0, 0);
    LOAD_A(0);

    f32x4 acc[4];
    #pragma unroll
    for (int j = 0; j < 4; ++j) acc[j] = (f32x4){0.f, 0.f, 0.f, 0.f};

    #pragma unroll
    for (int t = 0; t < 4; ++t) {
        const int cur = t & 1;
        // merge A(t) regs -> As[cur] (swizzled slots)
        {
            float w0 = wgt[t][0], w1 = wgt[t][1], w2 = wgt[t][2], w3 = wgt[t][3];
            #pragma unroll
            for (int j = 0; j < 2; ++j) {
                uint4 mv;
                unsigned* mp = (unsigned*)&mv;
                #pragma unroll
                for (int q = 0; q < 4; ++q) {
                    float lo = bf2f(ar[0][j].s[2*q])   * w0 + bf2f(ar[1][j].s[2*q])   * w1
                             + bf2f(ar[2][j].s[2*q])   * w2 + bf2f(ar[3][j].s[2*q])   * w3;
                    float hi = bf2f(ar[0][j].s[2*q+1]) * w0 + bf2f(ar[1][j].s[2*q+1]) * w1
                             + bf2f(ar[2][j].s[2*q+1]) * w2 + bf2f(ar[3][j].s[2*q+1]) * w3;
                    mp[q] = pack2(lo, hi);
                }
                *(uint4*)&As[cur][srow * 64 + (((s0 + j) ^ (srow & 7)) * 8)] = mv;
            }
        }
        __syncthreads();   // drains B(t) DMA + A-merge ds_writes
        if (t < 3) {       // T14: next tile's loads issued a full phase early
            ISSUE_B(cur ^ 1, (t + 1) * 64);
            LOAD_A(t + 1);
        }
        __builtin_amdgcn_s_setprio(1);
        #pragma unroll
        for (int ks = 0; ks < 2; ++ks) {
            bf16x8 a = ld_frag(&As[cur][(wave * 16 + l16) * 64
                                        + (((ks * 4 + quad) ^ x7) * 8)]);
            #pragma unroll
            for (int nt = 0; nt < 4; ++nt) {
                bf16x8 b = ld_frag(&Bs[cur][(nt * 16 + l16) * 64
                                            + (((ks * 4 + quad) ^ x7) * 8)]);
                acc[nt] = __builtin_amdgcn_mfma_f32_16x16x32_bf16(a, b, acc[nt], 0, 0, 0);
            }
        }
        __builtin_amdgcn_s_setprio(0);
    }

    float bv[4];
    #pragma unroll
    for (int nt = 0; nt < 4; ++nt) bv[nt] = bias[o0 + nt * 16 + l16];
    #pragma unroll
    for (int r = 0; r < 4; ++r) {
        int m = m0 + wave * 16 + quad * 4 + r;
        #pragma unroll
        for (int nt = 0; nt < 4; ++nt)
            out[(size_t)m * 256 + o0 + nt * 16 + l16] = acc[nt][r] + bv[nt];
    }
}

extern "C" void kernel_launch(void* const* d_in, const int* in_sizes, int n_in,
                              void* d_out, int out_size, void* d_ws, size_t ws_size,
                              hipStream_t stream) {
    const float* x       = (const float*)d_in[0];
    const float* Rm      = (const float*)d_in[1];
    const float* Pm      = (const float*)d_in[2];
    const float* qkv_w   = (const float*)d_in[3];
    const float* qkv_b   = (const float*)d_in[4];
    const float* proj_w  = (const float*)d_in[5];
    const float* proj_b  = (const float*)d_in[6];
    const float* pos_scl = (const float*)d_in[7];
    float* out = (float*)d_out;

    const size_t NE = (size_t)B_ * H_ * N_ * D_;   // 2,097,152
    unsigned short* opart = (unsigned short*)d_ws; // 4 partials = 16 MB
    unsigned short* qb    = opart + 4 * NE;        // 4 MB each
    unsigned short* kb    = qb   + NE;
    unsigned short* vtb   = kb   + NE;
    float*          mlb   = (float*)(vtb + NE);    // 4*16*2048 float2 = 1 MB
    unsigned short* eb    = (unsigned short*)(mlb + (size_t)4 * 16 * N_ * 2); // 64 KB
    unsigned short* wqb   = eb  + 2048 * 16;       // 384 KB
    unsigned short* wpb   = wqb + 768 * 256;       // 128 KB
    unsigned short* xb    = opart;                 // alias: xb dead before attn writes

    cvt_kernel<<<1160, 256, 0, stream>>>(x, qkv_w, proj_w, Pm, xb, wqb, wpb, eb);
    qkv_gemm<<<dim3(64, 6), 256, 0, stream>>>(xb, wqb, qkv_b, qb, kb, vtb);
    attn_kernel<<<dim3(32, 16, 4), 256, 0, stream>>>(qb, kb, vtb, eb, Rm, Pm, pos_scl, opart, mlb);
    proj_gemm<<<dim3(128, 4), 256, 0, stream>>>(opart, mlb, wpb, proj_b, out);
}

// Round 7
// 125.106 us; speedup vs baseline: 1.2389x; 1.0733x over previous
//
#include <hip/hip_runtime.h>
#include <hip/hip_bf16.h>

#define B_ 4
#define N_ 2048
#define C_ 256
#define H_ 4
#define D_ 64

typedef __attribute__((ext_vector_type(8))) short bf16x8;
typedef __attribute__((ext_vector_type(4))) float f32x4;

#define LOG2E 1.4426950408889634f

// f32 -> bf16 round-to-nearest-even (scalar)
static __device__ inline unsigned short f2bf(float f) {
    unsigned u = __builtin_bit_cast(unsigned, f);
    unsigned r = (u + 0x7fffu + ((u >> 16) & 1u)) >> 16;
    return (unsigned short)r;
}
static __device__ inline float bf2f(unsigned short h) {
    unsigned u = ((unsigned)h) << 16;
    return __builtin_bit_cast(float, u);
}
// packed pair f32 -> bf16x2
static __device__ inline unsigned pack2(float a, float b) {
    __hip_bfloat162 h = __float22bfloat162_rn(make_float2(a, b));
    unsigned u;
    __builtin_memcpy(&u, &h, 4);
    return u;
}
static __device__ inline bf16x8 ld_frag(const unsigned short* p) {
    return __builtin_bit_cast(bf16x8, *(const uint4*)p);
}
// async global->LDS DMA, 16B per lane, dest = ldsbase + lane*16
static __device__ inline void gload_lds16(const unsigned short* g, unsigned short* l) {
    __builtin_amdgcn_global_load_lds(
        (const __attribute__((address_space(1))) unsigned int*)(g),
        (__attribute__((address_space(3))) unsigned int*)(l),
        16, 0, 0);
}
// fmax with a DPP-permuted copy (VALU-latency cross-lane, 16-lane row scope)
template<int CTRL>
static __device__ inline float fmax_dpp(float x) {
    int yi = __builtin_amdgcn_update_dpp(0, __builtin_bit_cast(int, x),
                                         CTRL, 0xf, 0xf, true);
    return fmaxf(x, __builtin_bit_cast(float, yi));
}

// ---------------- cvt prepass: x / qkv_w / proj_w -> bf16; Pm -> ext table ----
// ext row (16 shorts) per key n: [ph0,ph1,ph2,pl0,pl1,pl2,ph0,ph1 | ph2,0,..,0]
__global__ __launch_bounds__(256) void cvt_kernel(
    const float* __restrict__ x, const float* __restrict__ qkv_w,
    const float* __restrict__ proj_w, const float* __restrict__ Pm,
    unsigned short* __restrict__ xb, unsigned short* __restrict__ wqb,
    unsigned short* __restrict__ wpb, unsigned short* __restrict__ eb)
{
    const int bid = blockIdx.x, tid = threadIdx.x;
    if (bid >= 1152) {
        const int n = (bid - 1152) * 256 + tid;
        const float* pp = Pm + n * 3;
        float p0 = pp[0], p1 = pp[1], p2 = pp[2];
        unsigned u0 = f2bf(p0), u1 = f2bf(p1), u2 = f2bf(p2);
        unsigned v0 = f2bf(p0 - bf2f((unsigned short)u0));
        unsigned v1 = f2bf(p1 - bf2f((unsigned short)u1));
        unsigned v2 = f2bf(p2 - bf2f((unsigned short)u2));
        uint4 lo, hi;
        lo.x = u0 | (u1 << 16); lo.y = u2 | (v0 << 16);
        lo.z = v1 | (v2 << 16); lo.w = u0 | (u1 << 16);
        hi.x = u2; hi.y = 0u; hi.z = 0u; hi.w = 0u;
        *(uint4*)&eb[n * 16 + 0] = lo;
        *(uint4*)&eb[n * 16 + 8] = hi;
        return;
    }
    const float* s; unsigned short* d; int i;
    if (bid < 1024)      { s = x;      d = xb;  i = (bid * 256 + tid) * 8; }
    else if (bid < 1120) { s = qkv_w;  d = wqb; i = ((bid - 1024) * 256 + tid) * 8; }
    else                 { s = proj_w; d = wpb; i = ((bid - 1120) * 256 + tid) * 8; }
    float4 a = *(const float4*)(s + i);
    float4 b = *(const float4*)(s + i + 4);
    uint4 u;
    u.x = pack2(a.x, a.y); u.y = pack2(a.z, a.w);
    u.z = pack2(b.x, b.y); u.w = pack2(b.z, b.w);
    *(uint4*)(d + i) = u;
}

// ---------------- QKV GEMM: bf16, 128x128 tile, BK=64, DMA double-buffer -----
// global_load_lds with pre-swizzled source (slot ^= row&7), one barrier/iter.
// Q pre-scaled by 0.125*log2e. V written transposed+permuted:
// vt[bh][d][n_perm], perm within 64-block: p = 4*(n&15)+((n>>4)&3).
__global__ __launch_bounds__(256) void qkv_gemm(
    const unsigned short* __restrict__ xb, const unsigned short* __restrict__ wb,
    const float* __restrict__ bias, unsigned short* __restrict__ qb,
    unsigned short* __restrict__ kb, unsigned short* __restrict__ vt)
{
    __shared__ __align__(16) unsigned short As[2][128 * 64]; // 32 KB
    __shared__ __align__(16) unsigned short Bs[2][128 * 64]; // 32 KB
    const int m0 = blockIdx.x * 128, o0 = blockIdx.y * 128;
    const int tid = threadIdx.x;
    const int wave = tid >> 6, lane = tid & 63, quad = lane >> 4, l16 = lane & 15;
    const int wy = wave >> 1, wx = wave & 1;
    const int x7 = l16 & 7;
    const int rl = lane >> 3, sl = lane & 7;      // 8 rows x 8 slots per DMA issue
    const int swz = (sl ^ rl) * 8;

    const unsigned short* aq0 = &xb[(size_t)(m0 + 32 * wave + rl) * 256 + swz];
    const unsigned short* bq0 = &wb[(size_t)(o0 + 32 * wave + rl) * 256 + swz];

    auto ISSUE = [&](int buf, int k0) {
        unsigned short* ad = &As[buf][(32 * wave) * 64];
        unsigned short* bd = &Bs[buf][(32 * wave) * 64];
        #pragma unroll
        for (int i = 0; i < 4; ++i) {
            gload_lds16(aq0 + (size_t)(8 * i) * 256 + k0, ad + (8 * i) * 64);
            gload_lds16(bq0 + (size_t)(8 * i) * 256 + k0, bd + (8 * i) * 64);
        }
    };

    f32x4 acc[4][4];
    #pragma unroll
    for (int i = 0; i < 4; ++i)
        #pragma unroll
        for (int j = 0; j < 4; ++j) acc[i][j] = (f32x4){0.f, 0.f, 0.f, 0.f};

    ISSUE(0, 0);   // prologue: tile 0 in flight

    #pragma unroll
    for (int t = 0; t < 4; ++t) {
        const int cur = t & 1;
        asm volatile("s_waitcnt vmcnt(0)" ::: "memory");   // tile t landed
        __builtin_amdgcn_s_barrier();
        __builtin_amdgcn_sched_barrier(0);
        if (t < 3) ISSUE(cur ^ 1, (t + 1) * 64);           // next tile in flight
        __builtin_amdgcn_s_setprio(1);
        #pragma unroll
        for (int ks = 0; ks < 2; ++ks) {
            bf16x8 a[4], b[4];
            #pragma unroll
            for (int mt = 0; mt < 4; ++mt)
                a[mt] = ld_frag(&As[cur][(wy * 64 + mt * 16 + l16) * 64
                                         + (((ks * 4 + quad) ^ x7) * 8)]);
            #pragma unroll
            for (int nt = 0; nt < 4; ++nt)
                b[nt] = ld_frag(&Bs[cur][(wx * 64 + nt * 16 + l16) * 64
                                         + (((ks * 4 + quad) ^ x7) * 8)]);
            #pragma unroll
            for (int mt = 0; mt < 4; ++mt)
                #pragma unroll
                for (int nt = 0; nt < 4; ++nt)
                    acc[mt][nt] = __builtin_amdgcn_mfma_f32_16x16x32_bf16(a[mt], b[nt], acc[mt][nt], 0, 0, 0);
        }
        __builtin_amdgcn_s_setprio(0);
    }

    const int sec = o0 + wx * 64;            // this wave's 64 output cols
    const int three = sec >> 8;
    const int h = (sec >> 6) & 3;
    const int b = m0 >> 11;
    float bv[4];
    #pragma unroll
    for (int nt = 0; nt < 4; ++nt) bv[nt] = bias[sec + nt * 16 + l16];

    if (three == 2) {
        // V: n = m0 + wy*64 + mt*16 + quad*4 + r; p = 16*quad + 4*r + mt (mt fast)
        const int n64 = (m0 + wy * 64) & 2047;
        const size_t bh64 = ((size_t)b * H_ + h) * 64;
        #pragma unroll
        for (int nt = 0; nt < 4; ++nt) {
            int d = nt * 16 + l16;
            #pragma unroll
            for (int r = 0; r < 4; ++r) {
                ushort4 v;
                v.x = f2bf(acc[0][nt][r] + bv[nt]);
                v.y = f2bf(acc[1][nt][r] + bv[nt]);
                v.z = f2bf(acc[2][nt][r] + bv[nt]);
                v.w = f2bf(acc[3][nt][r] + bv[nt]);
                *(ushort4*)&vt[(bh64 + d) * N_ + n64 + 16 * quad + 4 * r] = v;
            }
        }
    } else {
        unsigned short* dst = (three == 0) ? qb : kb;
        float sc = (three == 0) ? (0.125f * LOG2E) : 1.0f;
        #pragma unroll
        for (int mt = 0; mt < 4; ++mt)
            #pragma unroll
            for (int r = 0; r < 4; ++r) {
                int n = (m0 + wy * 64 + mt * 16 + quad * 4 + r) & 2047;
                size_t rowbase = (((size_t)b * H_ + h) * N_ + n) * D_;
                #pragma unroll
                for (int nt = 0; nt < 4; ++nt)
                    dst[rowbase + nt * 16 + l16] = f2bf((acc[mt][nt][r] + bv[nt]) * sc);
            }
    }
}

// ---------------- Flash attention: 8 waves / 128 queries, split-K x2 ---------
// 2-tile software pipeline (softmax+PV of tile jt-1 overlap tile jt's QK
// MFMAs); each K/V tile serves 128 queries. LDS 48 KB -> 3 blocks/CU
// capacity, grid 512 = 2/CU resident (2x the prior wave count).
#define LDK 64   // Ks/Vs/Ps row stride in shorts (128 B, 8 slots of 16 B)

__global__ __launch_bounds__(512) void attn_kernel(
    const unsigned short* __restrict__ qb, const unsigned short* __restrict__ kb,
    const unsigned short* __restrict__ vt, const unsigned short* __restrict__ eb,
    const float* __restrict__ Rm, const float* __restrict__ Pm,
    const float* __restrict__ ps_ptr,
    unsigned short* __restrict__ Opart, float* __restrict__ ml)
{
    __shared__ __align__(16) unsigned short Ks[2][64 * LDK];  // 16 KB
    __shared__ __align__(16) unsigned short Vs[2][64 * LDK];  // 16 KB
    __shared__ __align__(16) unsigned short Ps[128 * LDK];    // 16 KB

    const int bh = blockIdx.y;
    const int b = bh >> 2;
    const int i0 = blockIdx.x * 128;
    const int split = blockIdx.z;
    const int tid = threadIdx.x;
    const int wave = tid >> 6, lane = tid & 63;
    const int quad = lane >> 4, l16 = lane & 15;
    const int x7 = l16 & 7;
    const float ps = ps_ptr[0];

    const size_t base = (size_t)bh * N_ * D_;
    const unsigned short* qg = qb + base;
    const unsigned short* kg = kb + base;
    const unsigned short* vg = vt + base;   // rows of length N_

    const int jbeg = split * (N_ / 2);
    // NT = (N_/2)/64 = 16 tiles, hard-coded into the 7x2+1 step schedule below.

    // ---- DMA source pointers (pre-swizzled), advanced per tile ----
    // 8 waves x 8 rows: one gload_lds16 per wave covers its 8 rows.
    const int rl = lane >> 3, sl = lane & 7;
    const int swz = (sl ^ rl) * 8;
    const unsigned short* kq = kg + (size_t)(jbeg + wave * 8 + rl) * D_ + swz;
    const unsigned short* vq = vg + (size_t)(wave * 8 + rl) * N_ + jbeg + swz;
    const unsigned short* ep = eb + (size_t)(jbeg + l16) * 16 + (quad & 1) * 8;

    auto ISSUE_K = [&](int nb) {
        gload_lds16(kq, &Ks[nb][(wave * 8) * LDK]);
        kq += 64 * D_;
    };
    auto ISSUE_V = [&](int nb) {
        gload_lds16(vq, &Vs[nb][(wave * 8) * LDK]);
        vq += 64;
    };
    auto LOAD_E = [&](bf16x8 (&e)[4]) {
        #pragma unroll
        for (int t = 0; t < 4; ++t) e[t] = ld_frag(ep + t * 256);
        ep += 64 * 16;
    };

    // prologue: K(0) DMA + ext(0) regs
    ISSUE_K(0);
    bf16x8 eA[4], eB[4];
    LOAD_E(eA);

    // Q A-fragments (pre-scaled by 0.125*log2e)
    const int qrow = i0 + wave * 16 + l16;
    bf16x8 aq[3];
    #pragma unroll
    for (int ks = 0; ks < 2; ++ks)
        aq[ks] = ld_frag(&qg[(size_t)qrow * D_ + ks * 32 + quad * 8]);

    // A-side bias ext: a = ps*log2e*(R_b @ P_qrow), hi/lo split
    {
        float p0 = Pm[qrow * 3 + 0], p1 = Pm[qrow * 3 + 1], p2 = Pm[qrow * 3 + 2];
        float sc = ps * LOG2E;
        unsigned short ah[3], al[3];
        #pragma unroll
        for (int c = 0; c < 3; ++c) {
            float a = (Rm[b * 9 + c * 3 + 0] * p0 + Rm[b * 9 + c * 3 + 1] * p1
                     + Rm[b * 9 + c * 3 + 2] * p2) * sc;
            ah[c] = f2bf(a);
            al[c] = f2bf(a - bf2f(ah[c]));
        }
        bf16x8 e = (bf16x8){0,0,0,0,0,0,0,0};
        if (quad == 0) {
            e[0] = (short)ah[0]; e[1] = (short)ah[1]; e[2] = (short)ah[2];
            e[3] = (short)ah[0]; e[4] = (short)ah[1]; e[5] = (short)ah[2];
            e[6] = (short)al[0]; e[7] = (short)al[1];
        } else if (quad == 1) {
            e[0] = (short)al[2];
        }
        aq[2] = e;
    }

    const bf16x8 ones = (bf16x8){0x3F80,0x3F80,0x3F80,0x3F80,0x3F80,0x3F80,0x3F80,0x3F80};

    float m_run = -1e30f;
    f32x4 o_acc[4], lacc;
    #pragma unroll
    for (int t = 0; t < 4; ++t) o_acc[t] = (f32x4){0.f, 0.f, 0.f, 0.f};
    lacc = (f32x4){0.f, 0.f, 0.f, 0.f};

    f32x4 sA[4], sB[4];

    // S (log2-domain logits incl. bias) for the tile in Ks[kb_]
    auto S_COMPUTE = [&](f32x4 (&sc)[4], int kb_, bf16x8 (&ec)[4]) {
        __builtin_amdgcn_s_setprio(1);
        #pragma unroll
        for (int t = 0; t < 4; ++t) {
            const int rb = (l16 + 16 * t) * LDK;
            f32x4 c = {0.f, 0.f, 0.f, 0.f};
            #pragma unroll
            for (int ks = 0; ks < 2; ++ks) {
                bf16x8 bk = ld_frag(&Ks[kb_][rb + (((ks * 4 + quad) ^ x7) * 8)]);
                c = __builtin_amdgcn_mfma_f32_16x16x32_bf16(aq[ks], bk, c, 0, 0, 0);
            }
            c = __builtin_amdgcn_mfma_f32_16x16x32_bf16(aq[2], ec[t], c, 0, 0, 0);
            sc[t] = c;
        }
        __builtin_amdgcn_s_setprio(0);
    };

    // online softmax on a tile's logits (registers) -> Ps (wave-private rows)
    auto SOFTMAX = [&](f32x4 (&s)[4]) {
        float mt[4];
        #pragma unroll
        for (int t = 0; t < 4; ++t)   // max3-fusable chains
            mt[t] = fmaxf(fmaxf(fmaxf(s[t][0], s[t][1]), s[t][2]), s[t][3]);
        float mx = fmaxf(fmaxf(fmaxf(mt[0], mt[1]), mt[2]), mt[3]);
        mx = fmax_dpp<0xB1>(mx);    // quad_perm [1,0,3,2]  (xor 1)
        mx = fmax_dpp<0x4E>(mx);    // quad_perm [2,3,0,1]  (xor 2)
        mx = fmax_dpp<0x124>(mx);   // row_ror:4
        mx = fmax_dpp<0x128>(mx);   // row_ror:8
        if (__any(mx > m_run + 8.0f)) {       // defer-max rescale
            float mnew = fmaxf(m_run, mx);
            float alpha = exp2f(m_run - mnew);
            #pragma unroll
            for (int t = 0; t < 4; ++t)
                #pragma unroll
                for (int r = 0; r < 4; ++r)
                    o_acc[t][r] *= alpha;
            #pragma unroll
            for (int r = 0; r < 4; ++r) lacc[r] *= alpha;
            m_run = mnew;
        }
        #pragma unroll
        for (int r = 0; r < 4; ++r) {
            float p0 = exp2f(s[0][r] - m_run), p1 = exp2f(s[1][r] - m_run);
            float p2 = exp2f(s[2][r] - m_run), p3 = exp2f(s[3][r] - m_run);
            uint2 w;
            w.x = pack2(p0, p1);
            w.y = pack2(p2, p3);
            const int prow = quad * 4 + r;
            *(uint2*)&Ps[(wave * 16 + prow) * LDK
                         + (((l16 >> 1) ^ (prow & 7)) * 8) + (l16 & 1) * 4] = w;
        }
    };

    // O += P V; l += P . 1 (ones-MFMA); reads Vs[vb_]
    auto PV = [&](int vb_) {
        __builtin_amdgcn_s_setprio(1);
        #pragma unroll
        for (int ks = 0; ks < 2; ++ks) {
            bf16x8 ap = ld_frag(&Ps[(wave * 16 + l16) * LDK
                                    + (((ks * 4 + quad) ^ x7) * 8)]);
            #pragma unroll
            for (int t = 0; t < 4; ++t) {
                bf16x8 bv = ld_frag(&Vs[vb_][(l16 + 16 * t) * LDK
                                             + (((ks * 4 + quad) ^ x7) * 8)]);
                o_acc[t] = __builtin_amdgcn_mfma_f32_16x16x32_bf16(ap, bv, o_acc[t], 0, 0, 0);
            }
            lacc = __builtin_amdgcn_mfma_f32_16x16x32_bf16(ap, ones, lacc, 0, 0, 0);
        }
        __builtin_amdgcn_s_setprio(0);
    };

    // pipeline step for tile jt (cur = jt&1): softmax+PV of tile jt-1 overlap
    // the QK MFMAs of tile jt; single barrier per tile.
    auto STEP = [&](int cur, bool more, f32x4 (&snew)[4], f32x4 (&sold)[4],
                    bf16x8 (&euse)[4], bf16x8 (&eload)[4]) {
        asm volatile("s_waitcnt vmcnt(0)" ::: "memory");
        __builtin_amdgcn_s_barrier();
        __builtin_amdgcn_sched_barrier(0);
        if (more) ISSUE_K(cur ^ 1);   // K(jt+1)
        ISSUE_V(cur);                 // V(jt)
        SOFTMAX(sold);                // tile jt-1 -> Ps
        S_COMPUTE(snew, cur, euse);   // tile jt logits (hides Ps lgkm + fills matrix pipe)
        if (more) LOAD_E(eload);      // ext(jt+1)
        PV(cur ^ 1);                  // tile jt-1: Ps x Vs[(jt-1)&1]
    };

    // --- prologue step (tile 0): no softmax/PV yet ---
    asm volatile("s_waitcnt vmcnt(0)" ::: "memory");
    __builtin_amdgcn_s_barrier();
    __builtin_amdgcn_sched_barrier(0);
    ISSUE_K(1);      // K(1)
    ISSUE_V(0);      // V(0)
    S_COMPUTE(sA, 0, eA);
    LOAD_E(eB);      // ext(1)

    // --- tiles 1..15 (NT=16): 7 pairs + 1 tail ---
    #pragma unroll 1
    for (int it = 0; it < 7; ++it) {
        STEP(1, true, sB, sA, eB, eA);
        STEP(0, true, sA, sB, eA, eB);
    }
    STEP(1, false, sB, sA, eB, eA);

    // --- epilogue: finish tile 15 ---
    asm volatile("s_waitcnt vmcnt(0)" ::: "memory");
    __builtin_amdgcn_s_barrier();
    __builtin_amdgcn_sched_barrier(0);
    SOFTMAX(sB);
    PV(1);

    // store unnormalized partial O (bf16) + (m,l) per row
    const size_t pbase = (size_t)(split * 16 + bh) * N_;
    #pragma unroll
    for (int r = 0; r < 4; ++r) {
        int row = i0 + wave * 16 + quad * 4 + r;
        #pragma unroll
        for (int t = 0; t < 4; ++t)
            Opart[(pbase + row) * D_ + l16 + 16 * t] = f2bf(o_acc[t][r]);
        if (l16 == 0) {
            float2* mlp = (float2*)ml;
            mlp[pbase + row] = make_float2(m_run, lacc[r]);
        }
    }
}

// ---------------- Output projection: fused 2-way merge, BK=64, DMA B ---------
// A-merge on reg path with T14 split (loads issued one compute phase early);
// B tile via DMA double-buffer; one barrier per iter; XOR-swizzled LDS.
__global__ __launch_bounds__(256) void proj_gemm(
    const unsigned short* __restrict__ Opart, const float* __restrict__ ml,
    const unsigned short* __restrict__ wb, const float* __restrict__ bias,
    float* __restrict__ out)
{
    __shared__ __align__(16) unsigned short As[2][64 * 64]; // 16 KB
    __shared__ __align__(16) unsigned short Bs[2][64 * 64]; // 16 KB
    const int m0 = blockIdx.x * 64, o0 = blockIdx.y * 64;
    const int tid = threadIdx.x;
    const int wave = tid >> 6, lane = tid & 63, quad = lane >> 4, l16 = lane & 15;
    const int x7 = l16 & 7;
    const int rl = lane >> 3, sl = lane & 7;
    const int swz = (sl ^ rl) * 8;
    const float2* mlp = (const float2*)ml;

    const int srow = tid >> 2, sc16 = (tid & 3) * 16;   // A-merge: row, 16-col chunk
    const int s0 = (tid & 3) * 2;                       // first of 2 LDS slots
    const int sm = m0 + srow, sb = sm >> 11, sn = sm & 2047;

    // hoist 2-way merge weights per h
    float wgt[4][2];
    #pragma unroll
    for (int h = 0; h < 4; ++h) {
        size_t r1 = (size_t)(sb * 4 + h) * N_ + sn;
        float2 m0v = mlp[r1], m1v = mlp[r1 + 16 * N_];
        float mm = fmaxf(m0v.x, m1v.x);
        float w0 = exp2f(m0v.x - mm), w1 = exp2f(m1v.x - mm);
        float inv = 1.f / (m0v.y * w0 + m1v.y * w1);
        wgt[h][0] = w0 * inv; wgt[h][1] = w1 * inv;
    }

    const unsigned short* bq0 = &wb[(size_t)(o0 + 16 * wave + rl) * 256 + swz];
    auto ISSUE_B = [&](int buf, int k0) {
        unsigned short* bd = &Bs[buf][(16 * wave) * 64];
        gload_lds16(bq0 + k0,           bd);
        gload_lds16(bq0 + 8 * 256 + k0, bd + 8 * 64);
    };

    union U16 { uint4 u; unsigned short s[8]; };
    U16 ar[2][2];   // [split][8-short half] in-flight A sources
    auto LOAD_A = [&](int h) {
        size_t r1 = (size_t)(sb * 4 + h) * N_ + sn;
        #pragma unroll
        for (int s = 0; s < 2; ++s) {
            const unsigned short* p = &Opart[(r1 + (size_t)(16 * s) * N_) * D_ + sc16];
            ar[s][0].u = *(const uint4*)(p);
            ar[s][1].u = *(const uint4*)(p + 8);
        }
    };

    ISSUE_B(0, 0);
    LOAD_A(0);

    f32x4 acc[4];
    #pragma unroll
    for (int j = 0; j < 4; ++j) acc[j] = (f32x4){0.f, 0.f, 0.f, 0.f};

    #pragma unroll
    for (int t = 0; t < 4; ++t) {
        const int cur = t & 1;
        // merge A(t) regs -> As[cur] (swizzled slots)
        {
            float w0 = wgt[t][0], w1 = wgt[t][1];
            #pragma unroll
            for (int j = 0; j < 2; ++j) {
                uint4 mv;
                unsigned* mp = (unsigned*)&mv;
                #pragma unroll
                for (int q = 0; q < 4; ++q) {
                    float lo = bf2f(ar[0][j].s[2*q])   * w0 + bf2f(ar[1][j].s[2*q])   * w1;
                    float hi = bf2f(ar[0][j].s[2*q+1]) * w0 + bf2f(ar[1][j].s[2*q+1]) * w1;
                    mp[q] = pack2(lo, hi);
                }
                *(uint4*)&As[cur][srow * 64 + (((s0 + j) ^ (srow & 7)) * 8)] = mv;
            }
        }
        __syncthreads();   // drains B(t) DMA + A-merge ds_writes
        if (t < 3) {       // T14: next tile's loads issued a full phase early
            ISSUE_B(cur ^ 1, (t + 1) * 64);
            LOAD_A(t + 1);
        }
        __builtin_amdgcn_s_setprio(1);
        #pragma unroll
        for (int ks = 0; ks < 2; ++ks) {
            bf16x8 a = ld_frag(&As[cur][(wave * 16 + l16) * 64
                                        + (((ks * 4 + quad) ^ x7) * 8)]);
            #pragma unroll
            for (int nt = 0; nt < 4; ++nt) {
                bf16x8 b = ld_frag(&Bs[cur][(nt * 16 + l16) * 64
                                            + (((ks * 4 + quad) ^ x7) * 8)]);
                acc[nt] = __builtin_amdgcn_mfma_f32_16x16x32_bf16(a, b, acc[nt], 0, 0, 0);
            }
        }
        __builtin_amdgcn_s_setprio(0);
    }

    float bv[4];
    #pragma unroll
    for (int nt = 0; nt < 4; ++nt) bv[nt] = bias[o0 + nt * 16 + l16];
    #pragma unroll
    for (int r = 0; r < 4; ++r) {
        int m = m0 + wave * 16 + quad * 4 + r;
        #pragma unroll
        for (int nt = 0; nt < 4; ++nt)
            out[(size_t)m * 256 + o0 + nt * 16 + l16] = acc[nt][r] + bv[nt];
    }
}

extern "C" void kernel_launch(void* const* d_in, const int* in_sizes, int n_in,
                              void* d_out, int out_size, void* d_ws, size_t ws_size,
                              hipStream_t stream) {
    const float* x       = (const float*)d_in[0];
    const float* Rm      = (const float*)d_in[1];
    const float* Pm      = (const float*)d_in[2];
    const float* qkv_w   = (const float*)d_in[3];
    const float* qkv_b   = (const float*)d_in[4];
    const float* proj_w  = (const float*)d_in[5];
    const float* proj_b  = (const float*)d_in[6];
    const float* pos_scl = (const float*)d_in[7];
    float* out = (float*)d_out;

    const size_t NE = (size_t)B_ * H_ * N_ * D_;   // 2,097,152
    unsigned short* opart = (unsigned short*)d_ws; // 2 partials = 8 MB
    unsigned short* qb    = opart + 2 * NE;        // 4 MB each
    unsigned short* kb    = qb   + NE;
    unsigned short* vtb   = kb   + NE;
    float*          mlb   = (float*)(vtb + NE);    // 2*16*2048 float2 = 512 KB
    unsigned short* eb    = (unsigned short*)(mlb + (size_t)2 * 16 * N_ * 2); // 64 KB
    unsigned short* wqb   = eb  + 2048 * 16;       // 384 KB
    unsigned short* wpb   = wqb + 768 * 256;       // 128 KB
    unsigned short* xb    = opart;                 // alias: xb dead before attn writes

    cvt_kernel<<<1160, 256, 0, stream>>>(x, qkv_w, proj_w, Pm, xb, wqb, wpb, eb);
    qkv_gemm<<<dim3(64, 6), 256, 0, stream>>>(xb, wqb, qkv_b, qb, kb, vtb);
    attn_kernel<<<dim3(16, 16, 2), 512, 0, stream>>>(qb, kb, vtb, eb, Rm, Pm, pos_scl, opart, mlb);
    proj_gemm<<<dim3(128, 4), 256, 0, stream>>>(opart, mlb, wpb, proj_b, out);
}